// Round 2
// baseline (1178.959 us; speedup 1.0000x reference)
//
#include <hip/hip_runtime.h>

constexpr int N_NODES = 100000;
constexpr int E_EDGES = 1600000;
constexpr int IN_C = 128, HID_C = 64, OUT_C = 64;

// ---------------- zero fill ----------------
__global__ void zero_kernel(float* __restrict__ p, size_t n) {
    size_t i = (size_t)blockIdx.x * blockDim.x + threadIdx.x;
    if (i < n) p[i] = 0.0f;
}

// ---------------- degree ----------------
__global__ void deg_kernel(const int* __restrict__ dst, float* __restrict__ deg, int E) {
    int i = blockIdx.x * blockDim.x + threadIdx.x;
    if (i < E) atomicAdd(&deg[dst[i]], 1.0f);
}

__global__ void dinv_kernel(float* __restrict__ deg, int n) {
    int i = blockIdx.x * blockDim.x + threadIdx.x;
    if (i < n) deg[i] = rsqrtf(deg[i] + 1.0f);
}

// ---------------- dense GEMM: out[n][COUT] = in[n][CIN] @ W[CIN][COUT] (+bias) ----------------
template <int CIN, int COUT, bool BIAS>
__global__ void gemm_kernel(const float* __restrict__ in, const float* __restrict__ W,
                            const float* __restrict__ bias, float* __restrict__ out, int n) {
    constexpr int NB = 256 / COUT;  // nodes per block
    __shared__ float Wl[CIN * COUT];
    for (int i = threadIdx.x; i < CIN * COUT; i += 256) Wl[i] = W[i];
    __syncthreads();
    int node = blockIdx.x * NB + threadIdx.x / COUT;
    int c = threadIdx.x % COUT;
    if (node >= n) return;
    const float* row = in + (size_t)node * CIN;
    float acc = BIAS ? bias[c] : 0.0f;
#pragma unroll
    for (int k = 0; k < CIN; ++k) acc += row[k] * Wl[k * COUT + c];
    out[(size_t)node * COUT + c] = acc;
}

// ---------------- edge scatter: out[dst] += h[src] * dinv[src]*dinv[dst] ----------------
template <int C>
__global__ void scatter_kernel(const int* __restrict__ src, const int* __restrict__ dst,
                               const float* __restrict__ dinv, const float* __restrict__ h,
                               float* __restrict__ out, int E) {
    constexpr int EPB = 256 / C;  // edges per block
    int e = blockIdx.x * EPB + threadIdx.x / C;
    int c = threadIdx.x & (C - 1);
    if (e >= E) return;
    int s = src[e];
    int d = dst[e];
    float norm = dinv[s] * dinv[d];
    float v = h[(size_t)s * C + c] * norm;
    atomicAdd(&out[(size_t)d * C + c], v);
}

// ---------------- self-loop + bias (+relu) ----------------
template <int C, bool RELU>
__global__ void post_kernel(const float* __restrict__ agg, const float* __restrict__ h,
                            const float* __restrict__ dinv, const float* __restrict__ bias,
                            float* __restrict__ out, int n) {
    size_t i = (size_t)blockIdx.x * blockDim.x + threadIdx.x;
    if (i >= (size_t)n * C) return;
    int node = (int)(i / C);
    int c = (int)(i % C);
    float di = dinv[node];
    float v = agg[i] + h[i] * di * di + bias[c];
    out[i] = RELU ? fmaxf(v, 0.0f) : v;
}

extern "C" void kernel_launch(void* const* d_in, const int* in_sizes, int n_in,
                              void* d_out, int out_size, void* d_ws, size_t ws_size,
                              hipStream_t stream) {
    const float* x = (const float*)d_in[0];
    const int* ei = (const int*)d_in[1];   // int64 in reference -> int32 from harness
    const int* src = ei;
    const int* dst = ei + E_EDGES;
    const float* W1 = (const float*)d_in[2];
    const float* b1 = (const float*)d_in[3];
    const float* W2 = (const float*)d_in[4];
    const float* b2 = (const float*)d_in[5];
    const float* Wd = (const float*)d_in[6];
    const float* bd = (const float*)d_in[7];
    float* out = (float*)d_out;

    // workspace layout (floats): dinv[100096 pad] | bufA[N*64]   (~26 MB)
    // bufB aliases d_out's first N*64 floats (dead before decoder writes out).
    float* ws = (float*)d_ws;
    float* dinv = ws;
    float* bufA = ws + 100096;
    float* bufB = out;

    const int B = 256;
    const size_t NC = (size_t)N_NODES * 64;

    // degree -> dinv
    zero_kernel<<<(N_NODES + B - 1) / B, B, 0, stream>>>(dinv, N_NODES);
    deg_kernel<<<(E_EDGES + B - 1) / B, B, 0, stream>>>(dst, dinv, E_EDGES);
    dinv_kernel<<<(N_NODES + B - 1) / B, B, 0, stream>>>(dinv, N_NODES);

    // layer 1: h1 = x @ W1  -> bufA
    gemm_kernel<IN_C, HID_C, false><<<(N_NODES + 3) / 4, B, 0, stream>>>(x, W1, nullptr, bufA, N_NODES);
    // aggregate into bufB
    zero_kernel<<<(NC + B - 1) / B, B, 0, stream>>>(bufB, NC);
    scatter_kernel<64><<<(E_EDGES + 3) / 4, B, 0, stream>>>(src, dst, dinv, bufA, bufB, E_EDGES);
    // h1relu = relu(agg + h1*dinv^2 + b1) -> bufA
    post_kernel<64, true><<<(NC + B - 1) / B, B, 0, stream>>>(bufB, bufA, dinv, b1, bufA, N_NODES);

    // layer 2: h2 = h1relu @ W2 -> bufB
    gemm_kernel<HID_C, OUT_C, false><<<(N_NODES + 3) / 4, B, 0, stream>>>(bufA, W2, nullptr, bufB, N_NODES);
    // aggregate into bufA (h1relu consumed, buffer reusable)
    zero_kernel<<<(NC + B - 1) / B, B, 0, stream>>>(bufA, NC);
    scatter_kernel<64><<<(E_EDGES + 3) / 4, B, 0, stream>>>(src, dst, dinv, bufB, bufA, E_EDGES);
    // z = agg + h2*dinv^2 + b2 -> bufA
    post_kernel<64, false><<<(NC + B - 1) / B, B, 0, stream>>>(bufA, bufB, dinv, b2, bufA, N_NODES);

    // decoder: out = z @ Wd + bd   (overwrites all of d_out incl. bufB alias)
    gemm_kernel<OUT_C, IN_C, true><<<(N_NODES + 1) / 2, B, 0, stream>>>(bufA, Wd, bd, out, N_NODES);
}

// Round 3
// 653.457 us; speedup vs baseline: 1.8042x; 1.8042x over previous
//
#include <hip/hip_runtime.h>

constexpr int N_NODES = 100000;
constexpr int E_EDGES = 1600000;
constexpr int IN_C = 128, HID_C = 64, OUT_C = 64;
constexpr int NPAD = 100096;  // 391 * 256

// ---------------- small utility kernels ----------------
__global__ void zero_int_kernel(int* __restrict__ p, int n) {
    int i = blockIdx.x * blockDim.x + threadIdx.x;
    if (i < n) p[i] = 0;
}

__global__ void hist_kernel(const int* __restrict__ dst, int* __restrict__ count, int E) {
    int i = blockIdx.x * blockDim.x + threadIdx.x;
    if (i < E) atomicAdd(&count[dst[i]], 1);
}

// per-block sums of count -> partial[block]
__global__ void scan1_kernel(const int* __restrict__ count, int* __restrict__ partial, int n) {
    __shared__ int s[256];
    int t = threadIdx.x;
    int i = blockIdx.x * 256 + t;
    s[t] = (i < n) ? count[i] : 0;
    __syncthreads();
    for (int off = 128; off > 0; off >>= 1) {
        if (t < off) s[t] += s[t + off];
        __syncthreads();
    }
    if (t == 0) partial[blockIdx.x] = s[0];
}

// exclusive scan of partial[] (nb ~ 391, serial single thread is fine)
__global__ void scan2_kernel(int* __restrict__ partial, int nb) {
    if (blockIdx.x == 0 && threadIdx.x == 0) {
        int run = 0;
        for (int b = 0; b < nb; ++b) { int v = partial[b]; partial[b] = run; run += v; }
    }
}

// cursor[i] = global exclusive prefix of count; dinv[i] = rsqrt(count+1)
__global__ void scan3_kernel(const int* __restrict__ count, const int* __restrict__ partial,
                             int* __restrict__ cursor, float* __restrict__ dinv, int n) {
    __shared__ int s[256];
    int t = threadIdx.x;
    int i = blockIdx.x * 256 + t;
    int c = (i < n) ? count[i] : 0;
    s[t] = c;
    __syncthreads();
    for (int off = 1; off < 256; off <<= 1) {
        int v = (t >= off) ? s[t - off] : 0;
        __syncthreads();
        s[t] += v;
        __syncthreads();
    }
    if (i < n) {
        cursor[i] = partial[blockIdx.x] + s[t] - c;  // exclusive
        dinv[i] = rsqrtf((float)c + 1.0f);
    }
}

__global__ void fill_kernel(const int* __restrict__ src, const int* __restrict__ dst,
                            int* __restrict__ cursor, int* __restrict__ csr, int E) {
    int i = blockIdx.x * blockDim.x + threadIdx.x;
    if (i < E) {
        int pos = atomicAdd(&cursor[dst[i]], 1);
        csr[pos] = src[i];
    }
}

// ---------------- K1: g1 = (x @ W1) * dinv[node]  ----------------
// block 256 = 4 waves; each thread computes 4 nodes x 1 channel. grid = N/16.
__global__ __launch_bounds__(256) void gemm1_kernel(const float* __restrict__ x,
                                                    const float* __restrict__ W1,
                                                    const float* __restrict__ dinv,
                                                    float* __restrict__ g1) {
    __shared__ float Wl[IN_C * HID_C];  // 32 KB
    for (int i = threadIdx.x; i < IN_C * HID_C; i += 256) Wl[i] = W1[i];
    __syncthreads();
    int c = threadIdx.x & 63;
    int g = threadIdx.x >> 6;
    int n0 = blockIdx.x * 16 + g * 4;
    const float* r0 = x + (size_t)n0 * IN_C;
    const float* r1 = r0 + IN_C;
    const float* r2 = r1 + IN_C;
    const float* r3 = r2 + IN_C;
    float a0 = 0.f, a1 = 0.f, a2 = 0.f, a3 = 0.f;
#pragma unroll
    for (int k = 0; k < IN_C; k += 4) {
        float4 x0 = *(const float4*)(r0 + k);
        float4 x1 = *(const float4*)(r1 + k);
        float4 x2 = *(const float4*)(r2 + k);
        float4 x3 = *(const float4*)(r3 + k);
        float w;
        w = Wl[(k + 0) * 64 + c]; a0 += x0.x * w; a1 += x1.x * w; a2 += x2.x * w; a3 += x3.x * w;
        w = Wl[(k + 1) * 64 + c]; a0 += x0.y * w; a1 += x1.y * w; a2 += x2.y * w; a3 += x3.y * w;
        w = Wl[(k + 2) * 64 + c]; a0 += x0.z * w; a1 += x1.z * w; a2 += x2.z * w; a3 += x3.z * w;
        w = Wl[(k + 3) * 64 + c]; a0 += x0.w * w; a1 += x1.w * w; a2 += x2.w * w; a3 += x3.w * w;
    }
    g1[(size_t)(n0 + 0) * 64 + c] = a0 * dinv[n0 + 0];
    g1[(size_t)(n0 + 1) * 64 + c] = a1 * dinv[n0 + 1];
    g1[(size_t)(n0 + 2) * 64 + c] = a2 * dinv[n0 + 2];
    g1[(size_t)(n0 + 3) * 64 + c] = a3 * dinv[n0 + 3];
}

// ---------------- K2: fused gather(g1)+bias+relu -> @W2 -> *dinv -> g2 ----------------
// wave per dst node; lane = channel. grid = N/4, block 256.
__global__ __launch_bounds__(256) void fused1_kernel(const float* __restrict__ g1,
                                                     const int* __restrict__ csr,
                                                     const int* __restrict__ cursor,
                                                     const int* __restrict__ count,
                                                     const float* __restrict__ dinv,
                                                     const float* __restrict__ b1,
                                                     const float* __restrict__ W2,
                                                     float* __restrict__ g2) {
    __shared__ float zs[4][64];
    int lane = threadIdx.x & 63;
    int w = threadIdx.x >> 6;
    int d = blockIdx.x * 4 + w;
    int end = cursor[d];        // post-fill cursor = row end
    int cnt = count[d];
    int start = end - cnt;
    float dv = dinv[d];
    float acc = g1[(size_t)d * 64 + lane];  // self loop (g1[d] = h[d]*dinv[d])
    for (int base = start; base < end; base += 64) {
        int sv = (base + lane < end) ? csr[base + lane] : 0;
        int m = min(64, end - base);
        for (int j = 0; j < m; ++j) {
            int s = __shfl(sv, j);
            acc += g1[(size_t)s * 64 + lane];
        }
    }
    zs[w][lane] = fmaxf(dv * acc + b1[lane], 0.0f);  // h1relu row
    __syncthreads();
    float a = 0.f;
#pragma unroll 8
    for (int k = 0; k < HID_C; ++k) a += zs[w][k] * W2[k * 64 + lane];
    g2[(size_t)d * 64 + lane] = dv * a;
}

// ---------------- K3: fused gather(g2)+bias -> decoder @Wd + bd -> out ----------------
__global__ __launch_bounds__(256) void fused2_kernel(const float* __restrict__ g2,
                                                     const int* __restrict__ csr,
                                                     const int* __restrict__ cursor,
                                                     const int* __restrict__ count,
                                                     const float* __restrict__ dinv,
                                                     const float* __restrict__ b2,
                                                     const float* __restrict__ Wd,
                                                     const float* __restrict__ bd,
                                                     float* __restrict__ out) {
    __shared__ float zs[4][64];
    int lane = threadIdx.x & 63;
    int w = threadIdx.x >> 6;
    int d = blockIdx.x * 4 + w;
    int end = cursor[d];
    int cnt = count[d];
    int start = end - cnt;
    float dv = dinv[d];
    float acc = g2[(size_t)d * 64 + lane];
    for (int base = start; base < end; base += 64) {
        int sv = (base + lane < end) ? csr[base + lane] : 0;
        int m = min(64, end - base);
        for (int j = 0; j < m; ++j) {
            int s = __shfl(sv, j);
            acc += g2[(size_t)s * 64 + lane];
        }
    }
    zs[w][lane] = dv * acc + b2[lane];  // z row (no relu)
    __syncthreads();
    float a0 = bd[lane], a1 = bd[64 + lane];
#pragma unroll 8
    for (int k = 0; k < OUT_C; ++k) {
        float zk = zs[w][k];
        a0 += zk * Wd[k * 128 + lane];
        a1 += zk * Wd[k * 128 + 64 + lane];
    }
    out[(size_t)d * 128 + lane] = a0;
    out[(size_t)d * 128 + 64 + lane] = a1;
}

extern "C" void kernel_launch(void* const* d_in, const int* in_sizes, int n_in,
                              void* d_out, int out_size, void* d_ws, size_t ws_size,
                              hipStream_t stream) {
    const float* x = (const float*)d_in[0];
    const int* ei = (const int*)d_in[1];  // int64 ref -> int32 from harness
    const int* src = ei;
    const int* dst = ei + E_EDGES;
    const float* W1 = (const float*)d_in[2];
    const float* b1 = (const float*)d_in[3];
    const float* W2 = (const float*)d_in[4];
    const float* b2 = (const float*)d_in[5];
    const float* Wd = (const float*)d_in[6];
    const float* bd = (const float*)d_in[7];
    float* out = (float*)d_out;

    // ws layout (4-byte units):
    // count[NPAD] | cursor[NPAD] | dinv[NPAD] | partial[512] | csr[E] | g2[N*64]
    int* count = (int*)d_ws;
    int* cursor = count + NPAD;
    float* dinv = (float*)(cursor + NPAD);
    int* partial = (int*)(dinv + NPAD);
    int* csr = partial + 512;
    float* g2 = (float*)(csr + E_EDGES);   // byte offset 7,603,200 (256B aligned)
    float* g1 = out;                        // first N*64 floats of d_out; dead before K3

    const int B = 256;
    const int NB = (N_NODES + B - 1) / B;  // 391

    // ---- build CSR (by dst) + dinv ----
    zero_int_kernel<<<NB, B, 0, stream>>>(count, N_NODES);
    hist_kernel<<<E_EDGES / B, B, 0, stream>>>(dst, count, E_EDGES);
    scan1_kernel<<<NB, B, 0, stream>>>(count, partial, N_NODES);
    scan2_kernel<<<1, 64, 0, stream>>>(partial, NB);
    scan3_kernel<<<NB, B, 0, stream>>>(count, partial, cursor, dinv, N_NODES);
    fill_kernel<<<E_EDGES / B, B, 0, stream>>>(src, dst, cursor, csr, E_EDGES);

    // ---- layer 1 transform: g1 = (x @ W1) * dinv ----
    gemm1_kernel<<<N_NODES / 16, B, 0, stream>>>(x, W1, dinv, g1);
    // ---- fused: aggregate(g1) + b1 + relu, @W2, *dinv -> g2 ----
    fused1_kernel<<<N_NODES / 4, B, 0, stream>>>(g1, csr, cursor, count, dinv, b1, W2, g2);
    // ---- fused: aggregate(g2) + b2, decoder @Wd + bd -> out ----
    fused2_kernel<<<N_NODES / 4, B, 0, stream>>>(g2, csr, cursor, count, dinv, b2, Wd, bd, out);
}

// Round 4
// 547.675 us; speedup vs baseline: 2.1527x; 1.1931x over previous
//
#include <hip/hip_runtime.h>

constexpr int N_NODES = 100000;
constexpr int E_EDGES = 1600000;
constexpr int IN_C = 128, HID_C = 64, OUT_C = 64;
constexpr int NPAD = 100096;  // 391 * 256

// ---------------- small utility kernels ----------------
__global__ void zero_int_kernel(int* __restrict__ p, int n) {
    int i = blockIdx.x * blockDim.x + threadIdx.x;
    if (i < n) p[i] = 0;
}

__global__ void hist_kernel(const int* __restrict__ dst, int* __restrict__ count, int E) {
    int i = blockIdx.x * blockDim.x + threadIdx.x;
    if (i < E) atomicAdd(&count[dst[i]], 1);
}

// per-block sums of count -> partial[block]
__global__ void scan1_kernel(const int* __restrict__ count, int* __restrict__ partial, int n) {
    __shared__ int s[256];
    int t = threadIdx.x;
    int i = blockIdx.x * 256 + t;
    s[t] = (i < n) ? count[i] : 0;
    __syncthreads();
    for (int off = 128; off > 0; off >>= 1) {
        if (t < off) s[t] += s[t + off];
        __syncthreads();
    }
    if (t == 0) partial[blockIdx.x] = s[0];
}

// exclusive scan of partial[] (nb ~ 391, serial single thread is fine)
__global__ void scan2_kernel(int* __restrict__ partial, int nb) {
    if (blockIdx.x == 0 && threadIdx.x == 0) {
        int run = 0;
        for (int b = 0; b < nb; ++b) { int v = partial[b]; partial[b] = run; run += v; }
    }
}

// cursor[i] = global exclusive prefix of count; dinv[i] = rsqrt(count+1)
__global__ void scan3_kernel(const int* __restrict__ count, const int* __restrict__ partial,
                             int* __restrict__ cursor, float* __restrict__ dinv, int n) {
    __shared__ int s[256];
    int t = threadIdx.x;
    int i = blockIdx.x * 256 + t;
    int c = (i < n) ? count[i] : 0;
    s[t] = c;
    __syncthreads();
    for (int off = 1; off < 256; off <<= 1) {
        int v = (t >= off) ? s[t - off] : 0;
        __syncthreads();
        s[t] += v;
        __syncthreads();
    }
    if (i < n) {
        cursor[i] = partial[blockIdx.x] + s[t] - c;  // exclusive
        dinv[i] = rsqrtf((float)c + 1.0f);
    }
}

__global__ void fill_kernel(const int* __restrict__ src, const int* __restrict__ dst,
                            int* __restrict__ cursor, int* __restrict__ csr, int E) {
    int i = blockIdx.x * blockDim.x + threadIdx.x;
    if (i < E) {
        int pos = atomicAdd(&cursor[dst[i]], 1);
        csr[pos] = src[i];
    }
}

// ---------------- gather with 8-way MLP ----------------
__device__ __forceinline__ float gather_row(const float* __restrict__ g,
                                            const int* __restrict__ csr,
                                            int start, int end, int lane) {
    float a0 = 0.f, a1 = 0.f, a2 = 0.f, a3 = 0.f, a4 = 0.f, a5 = 0.f, a6 = 0.f, a7 = 0.f;
    for (int base = start; base < end; base += 64) {
        int m = min(64, end - base);
        int sv = (lane < m) ? csr[base + lane] : 0;
        int j = 0;
        for (; j + 8 <= m; j += 8) {
            int s0 = __shfl(sv, j + 0), s1 = __shfl(sv, j + 1);
            int s2 = __shfl(sv, j + 2), s3 = __shfl(sv, j + 3);
            int s4 = __shfl(sv, j + 4), s5 = __shfl(sv, j + 5);
            int s6 = __shfl(sv, j + 6), s7 = __shfl(sv, j + 7);
            a0 += g[(size_t)s0 * 64 + lane];
            a1 += g[(size_t)s1 * 64 + lane];
            a2 += g[(size_t)s2 * 64 + lane];
            a3 += g[(size_t)s3 * 64 + lane];
            a4 += g[(size_t)s4 * 64 + lane];
            a5 += g[(size_t)s5 * 64 + lane];
            a6 += g[(size_t)s6 * 64 + lane];
            a7 += g[(size_t)s7 * 64 + lane];
        }
        for (; j + 2 <= m; j += 2) {
            int s0 = __shfl(sv, j + 0), s1 = __shfl(sv, j + 1);
            a0 += g[(size_t)s0 * 64 + lane];
            a1 += g[(size_t)s1 * 64 + lane];
        }
        if (j < m) {
            int s0 = __shfl(sv, j);
            a2 += g[(size_t)s0 * 64 + lane];
        }
    }
    return ((a0 + a1) + (a2 + a3)) + ((a4 + a5) + (a6 + a7));
}

// ---------------- K1: g1 = (x @ W1) * dinv[node]  ----------------
__global__ __launch_bounds__(256) void gemm1_kernel(const float* __restrict__ x,
                                                    const float* __restrict__ W1,
                                                    const float* __restrict__ dinv,
                                                    float* __restrict__ g1) {
    __shared__ float Wl[IN_C * HID_C];  // 32 KB
    for (int i = threadIdx.x; i < IN_C * HID_C; i += 256) Wl[i] = W1[i];
    __syncthreads();
    int c = threadIdx.x & 63;
    int g = threadIdx.x >> 6;
    int n0 = blockIdx.x * 16 + g * 4;
    const float* r0 = x + (size_t)n0 * IN_C;
    const float* r1 = r0 + IN_C;
    const float* r2 = r1 + IN_C;
    const float* r3 = r2 + IN_C;
    float a0 = 0.f, a1 = 0.f, a2 = 0.f, a3 = 0.f;
#pragma unroll
    for (int k = 0; k < IN_C; k += 4) {
        float4 x0 = *(const float4*)(r0 + k);
        float4 x1 = *(const float4*)(r1 + k);
        float4 x2 = *(const float4*)(r2 + k);
        float4 x3 = *(const float4*)(r3 + k);
        float w;
        w = Wl[(k + 0) * 64 + c]; a0 += x0.x * w; a1 += x1.x * w; a2 += x2.x * w; a3 += x3.x * w;
        w = Wl[(k + 1) * 64 + c]; a0 += x0.y * w; a1 += x1.y * w; a2 += x2.y * w; a3 += x3.y * w;
        w = Wl[(k + 2) * 64 + c]; a0 += x0.z * w; a1 += x1.z * w; a2 += x2.z * w; a3 += x3.z * w;
        w = Wl[(k + 3) * 64 + c]; a0 += x0.w * w; a1 += x1.w * w; a2 += x2.w * w; a3 += x3.w * w;
    }
    g1[(size_t)(n0 + 0) * 64 + c] = a0 * dinv[n0 + 0];
    g1[(size_t)(n0 + 1) * 64 + c] = a1 * dinv[n0 + 1];
    g1[(size_t)(n0 + 2) * 64 + c] = a2 * dinv[n0 + 2];
    g1[(size_t)(n0 + 3) * 64 + c] = a3 * dinv[n0 + 3];
}

// ---------------- K2: fused gather(g1)+bias+relu -> @W2 -> *dinv -> g2 ----------------
__global__ __launch_bounds__(256) void fused1_kernel(const float* __restrict__ g1,
                                                     const int* __restrict__ csr,
                                                     const int* __restrict__ cursor,
                                                     const float* __restrict__ dinv,
                                                     const float* __restrict__ b1,
                                                     const float* __restrict__ W2,
                                                     float* __restrict__ g2) {
    __shared__ float zs[4][64];
    int lane = threadIdx.x & 63;
    int w = threadIdx.x >> 6;
    int d = blockIdx.x * 4 + w;
    int end = cursor[d];               // post-fill cursor[d] = row end
    int start = (d > 0) ? cursor[d - 1] : 0;
    float dv = dinv[d];
    float acc = g1[(size_t)d * 64 + lane] + gather_row(g1, csr, start, end, lane);
    zs[w][lane] = fmaxf(dv * acc + b1[lane], 0.0f);  // h1relu row (same-wave LDS RAW)
    float a = 0.f;
#pragma unroll 8
    for (int k = 0; k < HID_C; ++k) a += zs[w][k] * W2[k * 64 + lane];
    g2[(size_t)d * 64 + lane] = dv * a;
}

// ---------------- K3: fused gather(g2)+bias -> decoder @Wd + bd -> out ----------------
__global__ __launch_bounds__(256) void fused2_kernel(const float* __restrict__ g2,
                                                     const int* __restrict__ csr,
                                                     const int* __restrict__ cursor,
                                                     const float* __restrict__ dinv,
                                                     const float* __restrict__ b2,
                                                     const float* __restrict__ Wd,
                                                     const float* __restrict__ bd,
                                                     float* __restrict__ out) {
    __shared__ float zs[4][64];
    int lane = threadIdx.x & 63;
    int w = threadIdx.x >> 6;
    int d = blockIdx.x * 4 + w;
    int end = cursor[d];
    int start = (d > 0) ? cursor[d - 1] : 0;
    float dv = dinv[d];
    float acc = g2[(size_t)d * 64 + lane] + gather_row(g2, csr, start, end, lane);
    zs[w][lane] = dv * acc + b2[lane];  // z row
    float a0 = bd[lane], a1 = bd[64 + lane];
#pragma unroll 8
    for (int k = 0; k < OUT_C; ++k) {
        float zk = zs[w][k];
        a0 += zk * Wd[k * 128 + lane];
        a1 += zk * Wd[k * 128 + 64 + lane];
    }
    out[(size_t)d * 128 + lane] = a0;
    out[(size_t)d * 128 + 64 + lane] = a1;
}

extern "C" void kernel_launch(void* const* d_in, const int* in_sizes, int n_in,
                              void* d_out, int out_size, void* d_ws, size_t ws_size,
                              hipStream_t stream) {
    const float* x = (const float*)d_in[0];
    const int* ei = (const int*)d_in[1];  // int64 ref -> int32 from harness
    const int* src = ei;
    const int* dst = ei + E_EDGES;
    const float* W1 = (const float*)d_in[2];
    const float* b1 = (const float*)d_in[3];
    const float* W2 = (const float*)d_in[4];
    const float* b2 = (const float*)d_in[5];
    const float* Wd = (const float*)d_in[6];
    const float* bd = (const float*)d_in[7];
    float* out = (float*)d_out;

    // ws layout (4-byte units):
    // count[NPAD] | cursor[NPAD] | dinv[NPAD] | partial[512] | csr[E] | g2[N*64]
    int* count = (int*)d_ws;
    int* cursor = count + NPAD;
    float* dinv = (float*)(cursor + NPAD);
    int* partial = (int*)(dinv + NPAD);
    int* csr = partial + 512;
    float* g2 = (float*)(csr + E_EDGES);
    float* g1 = out;  // first N*64 floats of d_out; dead before fused2 writes out

    const int B = 256;
    const int NB = (N_NODES + B - 1) / B;  // 391

    // ---- build CSR (by dst) + dinv ----
    zero_int_kernel<<<NB, B, 0, stream>>>(count, N_NODES);
    hist_kernel<<<E_EDGES / B, B, 0, stream>>>(dst, count, E_EDGES);
    scan1_kernel<<<NB, B, 0, stream>>>(count, partial, N_NODES);
    scan2_kernel<<<1, 64, 0, stream>>>(partial, NB);
    scan3_kernel<<<NB, B, 0, stream>>>(count, partial, cursor, dinv, N_NODES);
    fill_kernel<<<E_EDGES / B, B, 0, stream>>>(src, dst, cursor, csr, E_EDGES);

    // ---- layer 1 transform: g1 = (x @ W1) * dinv ----
    gemm1_kernel<<<N_NODES / 16, B, 0, stream>>>(x, W1, dinv, g1);
    // ---- fused: aggregate(g1) + b1 + relu, @W2, *dinv -> g2 ----
    fused1_kernel<<<N_NODES / 4, B, 0, stream>>>(g1, csr, cursor, dinv, b1, W2, g2);
    // ---- fused: aggregate(g2) + b2, decoder @Wd + bd -> out ----
    fused2_kernel<<<N_NODES / 4, B, 0, stream>>>(g2, csr, cursor, dinv, b2, Wd, bd, out);
}

// Round 5
// 535.561 us; speedup vs baseline: 2.2014x; 1.0226x over previous
//
#include <hip/hip_runtime.h>

constexpr int N_NODES = 100000;
constexpr int E_EDGES = 1600000;
constexpr int IN_C = 128, HID_C = 64, OUT_C = 64;
constexpr int NPAD = 100096;  // 391 * 256

// ---------------- bf16 helpers (RNE) ----------------
__device__ __forceinline__ unsigned short f2bf(float f) {
    unsigned int u = __float_as_uint(f);
    unsigned int r = (u + 0x7FFFu + ((u >> 16) & 1u)) >> 16;
    return (unsigned short)r;
}
__device__ __forceinline__ float bf2f(unsigned short b) {
    return __uint_as_float((unsigned int)b << 16);
}

// ---------------- small utility kernels ----------------
__global__ void zero_int_kernel(int* __restrict__ p, int n) {
    int i = blockIdx.x * blockDim.x + threadIdx.x;
    if (i < n) p[i] = 0;
}

__global__ void hist_kernel(const int* __restrict__ dst, int* __restrict__ count, int E) {
    int i = blockIdx.x * blockDim.x + threadIdx.x;
    if (i < E) atomicAdd(&count[dst[i]], 1);
}

__global__ void scan1_kernel(const int* __restrict__ count, int* __restrict__ partial, int n) {
    __shared__ int s[256];
    int t = threadIdx.x;
    int i = blockIdx.x * 256 + t;
    s[t] = (i < n) ? count[i] : 0;
    __syncthreads();
    for (int off = 128; off > 0; off >>= 1) {
        if (t < off) s[t] += s[t + off];
        __syncthreads();
    }
    if (t == 0) partial[blockIdx.x] = s[0];
}

__global__ void scan2_kernel(int* __restrict__ partial, int nb) {
    if (blockIdx.x == 0 && threadIdx.x == 0) {
        int run = 0;
        for (int b = 0; b < nb; ++b) { int v = partial[b]; partial[b] = run; run += v; }
    }
}

__global__ void scan3_kernel(const int* __restrict__ count, const int* __restrict__ partial,
                             int* __restrict__ cursor, float* __restrict__ dinv, int n) {
    __shared__ int s[256];
    int t = threadIdx.x;
    int i = blockIdx.x * 256 + t;
    int c = (i < n) ? count[i] : 0;
    s[t] = c;
    __syncthreads();
    for (int off = 1; off < 256; off <<= 1) {
        int v = (t >= off) ? s[t - off] : 0;
        __syncthreads();
        s[t] += v;
        __syncthreads();
    }
    if (i < n) {
        cursor[i] = partial[blockIdx.x] + s[t] - c;  // exclusive
        dinv[i] = rsqrtf((float)c + 1.0f);
    }
}

__global__ void fill_kernel(const int* __restrict__ src, const int* __restrict__ dst,
                            int* __restrict__ cursor, int* __restrict__ csr, int E) {
    int i = blockIdx.x * blockDim.x + threadIdx.x;
    if (i < E) {
        int pos = atomicAdd(&cursor[dst[i]], 1);
        csr[pos] = src[i];
    }
}

// ---------------- gather (bf16 table) with 8-way MLP ----------------
__device__ __forceinline__ float gather_row(const unsigned short* __restrict__ g,
                                            const int* __restrict__ csr,
                                            int start, int end, int lane) {
    float a0 = 0.f, a1 = 0.f, a2 = 0.f, a3 = 0.f, a4 = 0.f, a5 = 0.f, a6 = 0.f, a7 = 0.f;
    for (int base = start; base < end; base += 64) {
        int m = min(64, end - base);
        int sv = (lane < m) ? csr[base + lane] : 0;
        int j = 0;
        for (; j + 8 <= m; j += 8) {
            int s0 = __shfl(sv, j + 0), s1 = __shfl(sv, j + 1);
            int s2 = __shfl(sv, j + 2), s3 = __shfl(sv, j + 3);
            int s4 = __shfl(sv, j + 4), s5 = __shfl(sv, j + 5);
            int s6 = __shfl(sv, j + 6), s7 = __shfl(sv, j + 7);
            unsigned short v0 = g[(size_t)s0 * 64 + lane];
            unsigned short v1 = g[(size_t)s1 * 64 + lane];
            unsigned short v2 = g[(size_t)s2 * 64 + lane];
            unsigned short v3 = g[(size_t)s3 * 64 + lane];
            unsigned short v4 = g[(size_t)s4 * 64 + lane];
            unsigned short v5 = g[(size_t)s5 * 64 + lane];
            unsigned short v6 = g[(size_t)s6 * 64 + lane];
            unsigned short v7 = g[(size_t)s7 * 64 + lane];
            a0 += bf2f(v0); a1 += bf2f(v1); a2 += bf2f(v2); a3 += bf2f(v3);
            a4 += bf2f(v4); a5 += bf2f(v5); a6 += bf2f(v6); a7 += bf2f(v7);
        }
        for (; j + 2 <= m; j += 2) {
            int s0 = __shfl(sv, j + 0), s1 = __shfl(sv, j + 1);
            a0 += bf2f(g[(size_t)s0 * 64 + lane]);
            a1 += bf2f(g[(size_t)s1 * 64 + lane]);
        }
        if (j < m) {
            int s0 = __shfl(sv, j);
            a2 += bf2f(g[(size_t)s0 * 64 + lane]);
        }
    }
    return ((a0 + a1) + (a2 + a3)) + ((a4 + a5) + (a6 + a7));
}

// ---------------- K1: g1 = bf16((x @ W1) * dinv[node]) ----------------
__global__ __launch_bounds__(256) void gemm1_kernel(const float* __restrict__ x,
                                                    const float* __restrict__ W1,
                                                    const float* __restrict__ dinv,
                                                    unsigned short* __restrict__ g1) {
    __shared__ float Wl[IN_C * HID_C];  // 32 KB
    for (int i = threadIdx.x; i < IN_C * HID_C; i += 256) Wl[i] = W1[i];
    __syncthreads();
    int c = threadIdx.x & 63;
    int g = threadIdx.x >> 6;
    int n0 = blockIdx.x * 16 + g * 4;
    const float* r0 = x + (size_t)n0 * IN_C;
    const float* r1 = r0 + IN_C;
    const float* r2 = r1 + IN_C;
    const float* r3 = r2 + IN_C;
    float a0 = 0.f, a1 = 0.f, a2 = 0.f, a3 = 0.f;
#pragma unroll
    for (int k = 0; k < IN_C; k += 4) {
        float4 x0 = *(const float4*)(r0 + k);
        float4 x1 = *(const float4*)(r1 + k);
        float4 x2 = *(const float4*)(r2 + k);
        float4 x3 = *(const float4*)(r3 + k);
        float w;
        w = Wl[(k + 0) * 64 + c]; a0 += x0.x * w; a1 += x1.x * w; a2 += x2.x * w; a3 += x3.x * w;
        w = Wl[(k + 1) * 64 + c]; a0 += x0.y * w; a1 += x1.y * w; a2 += x2.y * w; a3 += x3.y * w;
        w = Wl[(k + 2) * 64 + c]; a0 += x0.z * w; a1 += x1.z * w; a2 += x2.z * w; a3 += x3.z * w;
        w = Wl[(k + 3) * 64 + c]; a0 += x0.w * w; a1 += x1.w * w; a2 += x2.w * w; a3 += x3.w * w;
    }
    g1[(size_t)(n0 + 0) * 64 + c] = f2bf(a0 * dinv[n0 + 0]);
    g1[(size_t)(n0 + 1) * 64 + c] = f2bf(a1 * dinv[n0 + 1]);
    g1[(size_t)(n0 + 2) * 64 + c] = f2bf(a2 * dinv[n0 + 2]);
    g1[(size_t)(n0 + 3) * 64 + c] = f2bf(a3 * dinv[n0 + 3]);
}

// ---------------- K2: fused gather(g1)+bias+relu -> @W2 -> *dinv -> g2(bf16) ----------------
__global__ __launch_bounds__(256) void fused1_kernel(const unsigned short* __restrict__ g1,
                                                     const int* __restrict__ csr,
                                                     const int* __restrict__ cursor,
                                                     const float* __restrict__ dinv,
                                                     const float* __restrict__ b1,
                                                     const float* __restrict__ W2,
                                                     unsigned short* __restrict__ g2) {
    __shared__ float zs[4][64];
    int lane = threadIdx.x & 63;
    int w = threadIdx.x >> 6;
    int d = blockIdx.x * 4 + w;
    int end = cursor[d];               // post-fill cursor[d] = row end
    int start = (d > 0) ? cursor[d - 1] : 0;
    float dv = dinv[d];
    float acc = bf2f(g1[(size_t)d * 64 + lane]) + gather_row(g1, csr, start, end, lane);
    zs[w][lane] = fmaxf(dv * acc + b1[lane], 0.0f);  // h1relu row (same-wave LDS RAW)
    float a = 0.f;
#pragma unroll 8
    for (int k = 0; k < HID_C; ++k) a += zs[w][k] * W2[k * 64 + lane];
    g2[(size_t)d * 64 + lane] = f2bf(dv * a);
}

// ---------------- K3: fused gather(g2)+bias -> decoder @Wd + bd -> out ----------------
__global__ __launch_bounds__(256) void fused2_kernel(const unsigned short* __restrict__ g2,
                                                     const int* __restrict__ csr,
                                                     const int* __restrict__ cursor,
                                                     const float* __restrict__ dinv,
                                                     const float* __restrict__ b2,
                                                     const float* __restrict__ Wd,
                                                     const float* __restrict__ bd,
                                                     float* __restrict__ out) {
    __shared__ float zs[4][64];
    int lane = threadIdx.x & 63;
    int w = threadIdx.x >> 6;
    int d = blockIdx.x * 4 + w;
    int end = cursor[d];
    int start = (d > 0) ? cursor[d - 1] : 0;
    float dv = dinv[d];
    float acc = bf2f(g2[(size_t)d * 64 + lane]) + gather_row(g2, csr, start, end, lane);
    zs[w][lane] = dv * acc + b2[lane];  // z row
    float a0 = bd[lane], a1 = bd[64 + lane];
#pragma unroll 8
    for (int k = 0; k < OUT_C; ++k) {
        float zk = zs[w][k];
        a0 += zk * Wd[k * 128 + lane];
        a1 += zk * Wd[k * 128 + 64 + lane];
    }
    out[(size_t)d * 128 + lane] = a0;
    out[(size_t)d * 128 + 64 + lane] = a1;
}

extern "C" void kernel_launch(void* const* d_in, const int* in_sizes, int n_in,
                              void* d_out, int out_size, void* d_ws, size_t ws_size,
                              hipStream_t stream) {
    const float* x = (const float*)d_in[0];
    const int* ei = (const int*)d_in[1];  // int64 ref -> int32 from harness
    const int* src = ei;
    const int* dst = ei + E_EDGES;
    const float* W1 = (const float*)d_in[2];
    const float* b1 = (const float*)d_in[3];
    const float* W2 = (const float*)d_in[4];
    const float* b2 = (const float*)d_in[5];
    const float* Wd = (const float*)d_in[6];
    const float* bd = (const float*)d_in[7];
    float* out = (float*)d_out;

    // ws layout (4-byte units):
    // count[NPAD] | cursor[NPAD] | dinv[NPAD] | partial[512] | csr[E] | g2[N*64 bf16]
    int* count = (int*)d_ws;
    int* cursor = count + NPAD;
    float* dinv = (float*)(cursor + NPAD);
    int* partial = (int*)(dinv + NPAD);
    int* csr = partial + 512;
    unsigned short* g2 = (unsigned short*)(csr + E_EDGES);
    unsigned short* g1 = (unsigned short*)out;  // first 12.8MB of d_out; dead before fused2

    const int B = 256;
    const int NB = (N_NODES + B - 1) / B;  // 391

    // ---- build CSR (by dst) + dinv ----
    zero_int_kernel<<<NB, B, 0, stream>>>(count, N_NODES);
    hist_kernel<<<E_EDGES / B, B, 0, stream>>>(dst, count, E_EDGES);
    scan1_kernel<<<NB, B, 0, stream>>>(count, partial, N_NODES);
    scan2_kernel<<<1, 64, 0, stream>>>(partial, NB);
    scan3_kernel<<<NB, B, 0, stream>>>(count, partial, cursor, dinv, N_NODES);
    fill_kernel<<<E_EDGES / B, B, 0, stream>>>(src, dst, cursor, csr, E_EDGES);

    // ---- layer 1 transform: g1 = bf16((x @ W1) * dinv) ----
    gemm1_kernel<<<N_NODES / 16, B, 0, stream>>>(x, W1, dinv, g1);
    // ---- fused: aggregate(g1) + b1 + relu, @W2, *dinv -> g2 ----
    fused1_kernel<<<N_NODES / 4, B, 0, stream>>>(g1, csr, cursor, dinv, b1, W2, g2);
    // ---- fused: aggregate(g2) + b2, decoder @Wd + bd -> out ----
    fused2_kernel<<<N_NODES / 4, B, 0, stream>>>(g2, csr, cursor, dinv, b2, Wd, bd, out);
}

// Round 6
// 454.242 us; speedup vs baseline: 2.5954x; 1.1790x over previous
//
#include <hip/hip_runtime.h>

constexpr int N_NODES = 100000;
constexpr int E_EDGES = 1600000;
constexpr int IN_C = 128, HID_C = 64, OUT_C = 64;
constexpr int NPAD = 100096;      // 391 * 256
constexpr int PADMAX = 2400256;   // >= E + 7*N
constexpr int DUMMY = N_NODES;    // index of the all-zero row in g tables

// ---------------- bf16 helpers (RNE) ----------------
__device__ __forceinline__ unsigned short f2bf(float f) {
    unsigned int u = __float_as_uint(f);
    unsigned int r = (u + 0x7FFFu + ((u >> 16) & 1u)) >> 16;
    return (unsigned short)r;
}
__device__ __forceinline__ float bf2f(unsigned short b) {
    return __uint_as_float((unsigned int)b << 16);
}

// ---------------- small utility kernels ----------------
__global__ void zero_int_kernel(int* __restrict__ p, int n) {
    int i = blockIdx.x * blockDim.x + threadIdx.x;
    if (i < n) p[i] = 0;
}

__global__ void hist_kernel(const int* __restrict__ dst, int* __restrict__ count, int E) {
    int i = blockIdx.x * blockDim.x + threadIdx.x;
    if (i < E) atomicAdd(&count[dst[i]], 1);
}

// per-block sums of PADDED counts -> partial[block]
__global__ void scan1_kernel(const int* __restrict__ count, int* __restrict__ partial, int n) {
    __shared__ int s[256];
    int t = threadIdx.x;
    int i = blockIdx.x * 256 + t;
    int c = (i < n) ? count[i] : 0;
    s[t] = (c + 7) & ~7;
    __syncthreads();
    for (int off = 128; off > 0; off >>= 1) {
        if (t < off) s[t] += s[t + off];
        __syncthreads();
    }
    if (t == 0) partial[blockIdx.x] = s[0];
}

// serial exclusive scan of partial[]; also zero row N of g1/g2 tables
__global__ void scan2_kernel(int* __restrict__ partial, int nb,
                             unsigned short* __restrict__ g1, unsigned short* __restrict__ g2) {
    if (threadIdx.x == 0) {
        int run = 0;
        for (int b = 0; b < nb; ++b) { int v = partial[b]; partial[b] = run; run += v; }
    }
    // zero row N (128 ushorts = 64 uints each)
    unsigned int* r1 = (unsigned int*)(g1 + (size_t)N_NODES * 64);
    unsigned int* r2 = (unsigned int*)(g2 + (size_t)N_NODES * 64);
    if (threadIdx.x < 32) { r1[threadIdx.x] = 0u; r2[threadIdx.x] = 0u; }
}

// cursor[i] = padded-exclusive prefix (fill start); rowend[i] = padded row end; dinv
__global__ void scan3_kernel(const int* __restrict__ count, const int* __restrict__ partial,
                             int* __restrict__ cursor, int* __restrict__ rowend,
                             float* __restrict__ dinv, int n) {
    __shared__ int s[256];
    int t = threadIdx.x;
    int i = blockIdx.x * 256 + t;
    int c = (i < n) ? count[i] : 0;
    int pc = (c + 7) & ~7;
    s[t] = pc;
    __syncthreads();
    for (int off = 1; off < 256; off <<= 1) {
        int v = (t >= off) ? s[t - off] : 0;
        __syncthreads();
        s[t] += v;
        __syncthreads();
    }
    if (i < n) {
        int pstart = partial[blockIdx.x] + s[t] - pc;  // exclusive padded scan
        cursor[i] = pstart;
        rowend[i] = pstart + pc;
        dinv[i] = rsqrtf((float)c + 1.0f);
    }
}

__global__ void fill_kernel(const int* __restrict__ src, const int* __restrict__ dst,
                            int* __restrict__ cursor, int* __restrict__ csr, int E) {
    int i = blockIdx.x * blockDim.x + threadIdx.x;
    if (i < E) {
        int pos = atomicAdd(&cursor[dst[i]], 1);
        csr[pos] = src[i];
    }
}

// pad each row's tail [cursor[i], rowend[i]) with DUMMY
__global__ void pad_kernel(const int* __restrict__ cursor, const int* __restrict__ rowend,
                           int* __restrict__ csr, int n) {
    int i = blockIdx.x * blockDim.x + threadIdx.x;
    if (i < n) {
        int e = cursor[i], re = rowend[i];
        for (int p = e; p < re; ++p) csr[p] = DUMMY;
    }
}

// ---------------- 4-row contiguous-span gather, 8-deep MLP, uniform routing ----------------
__device__ __forceinline__ void gather4(const unsigned short* __restrict__ g,
                                        const int* __restrict__ csr,
                                        int S, int e0, int e1, int e2, int e3, int lane,
                                        float& A0, float& A1, float& A2, float& A3) {
    float a0 = 0.f, a1 = 0.f, a2 = 0.f, a3 = 0.f;
    for (int base = S; base < e3; base += 64) {
        int m = min(64, e3 - base);            // multiple of 8 (rows are 8-aligned)
        int sv = (lane < m) ? csr[base + lane] : 0;
        for (int j = 0; j < m; j += 8) {
            int p = base + j;                  // uniform; whole 8-group in one row
            int s0 = __shfl(sv, j + 0), s1 = __shfl(sv, j + 1);
            int s2 = __shfl(sv, j + 2), s3 = __shfl(sv, j + 3);
            int s4 = __shfl(sv, j + 4), s5 = __shfl(sv, j + 5);
            int s6 = __shfl(sv, j + 6), s7 = __shfl(sv, j + 7);
            float f0 = bf2f(g[(size_t)s0 * 64 + lane]);
            float f1 = bf2f(g[(size_t)s1 * 64 + lane]);
            float f2 = bf2f(g[(size_t)s2 * 64 + lane]);
            float f3 = bf2f(g[(size_t)s3 * 64 + lane]);
            float f4 = bf2f(g[(size_t)s4 * 64 + lane]);
            float f5 = bf2f(g[(size_t)s5 * 64 + lane]);
            float f6 = bf2f(g[(size_t)s6 * 64 + lane]);
            float f7 = bf2f(g[(size_t)s7 * 64 + lane]);
            float t = ((f0 + f1) + (f2 + f3)) + ((f4 + f5) + (f6 + f7));
            if (p < e1) { if (p < e0) a0 += t; else a1 += t; }
            else        { if (p < e2) a2 += t; else a3 += t; }
        }
    }
    A0 = a0; A1 = a1; A2 = a2; A3 = a3;
}

// ---------------- K1: g1 = bf16((x @ W1) * dinv[node]) ----------------
__global__ __launch_bounds__(256) void gemm1_kernel(const float* __restrict__ x,
                                                    const float* __restrict__ W1,
                                                    const float* __restrict__ dinv,
                                                    unsigned short* __restrict__ g1) {
    __shared__ float Wl[IN_C * HID_C];  // 32 KB
    for (int i = threadIdx.x; i < IN_C * HID_C; i += 256) Wl[i] = W1[i];
    __syncthreads();
    int c = threadIdx.x & 63;
    int g = threadIdx.x >> 6;
    int n0 = blockIdx.x * 16 + g * 4;
    const float* r0 = x + (size_t)n0 * IN_C;
    const float* r1 = r0 + IN_C;
    const float* r2 = r1 + IN_C;
    const float* r3 = r2 + IN_C;
    float a0 = 0.f, a1 = 0.f, a2 = 0.f, a3 = 0.f;
#pragma unroll
    for (int k = 0; k < IN_C; k += 4) {
        float4 x0 = *(const float4*)(r0 + k);
        float4 x1 = *(const float4*)(r1 + k);
        float4 x2 = *(const float4*)(r2 + k);
        float4 x3 = *(const float4*)(r3 + k);
        float w;
        w = Wl[(k + 0) * 64 + c]; a0 += x0.x * w; a1 += x1.x * w; a2 += x2.x * w; a3 += x3.x * w;
        w = Wl[(k + 1) * 64 + c]; a0 += x0.y * w; a1 += x1.y * w; a2 += x2.y * w; a3 += x3.y * w;
        w = Wl[(k + 2) * 64 + c]; a0 += x0.z * w; a1 += x1.z * w; a2 += x2.z * w; a3 += x3.z * w;
        w = Wl[(k + 3) * 64 + c]; a0 += x0.w * w; a1 += x1.w * w; a2 += x2.w * w; a3 += x3.w * w;
    }
    g1[(size_t)(n0 + 0) * 64 + c] = f2bf(a0 * dinv[n0 + 0]);
    g1[(size_t)(n0 + 1) * 64 + c] = f2bf(a1 * dinv[n0 + 1]);
    g1[(size_t)(n0 + 2) * 64 + c] = f2bf(a2 * dinv[n0 + 2]);
    g1[(size_t)(n0 + 3) * 64 + c] = f2bf(a3 * dinv[n0 + 3]);
}

// ---------------- K2: 4-row fused gather(g1)+bias+relu -> @W2 -> *dinv -> g2(bf16) ----------------
__global__ __launch_bounds__(256) void fused1_kernel(const unsigned short* __restrict__ g1,
                                                     const int* __restrict__ csr,
                                                     const int* __restrict__ rowend,
                                                     const float* __restrict__ dinv,
                                                     const float* __restrict__ b1,
                                                     const float* __restrict__ W2,
                                                     unsigned short* __restrict__ g2) {
    __shared__ float zs[16][64];
    int lane = threadIdx.x & 63;
    int w = threadIdx.x >> 6;
    int d0 = blockIdx.x * 16 + w * 4;
    int S  = __builtin_amdgcn_readfirstlane((d0 > 0) ? rowend[d0 - 1] : 0);
    int e0 = __builtin_amdgcn_readfirstlane(rowend[d0 + 0]);
    int e1 = __builtin_amdgcn_readfirstlane(rowend[d0 + 1]);
    int e2 = __builtin_amdgcn_readfirstlane(rowend[d0 + 2]);
    int e3 = __builtin_amdgcn_readfirstlane(rowend[d0 + 3]);
    float dv0 = dinv[d0 + 0], dv1 = dinv[d0 + 1], dv2 = dinv[d0 + 2], dv3 = dinv[d0 + 3];
    float b1v = b1[lane];
    float a0, a1, a2, a3;
    gather4(g1, csr, S, e0, e1, e2, e3, lane, a0, a1, a2, a3);
    a0 += bf2f(g1[(size_t)(d0 + 0) * 64 + lane]);
    a1 += bf2f(g1[(size_t)(d0 + 1) * 64 + lane]);
    a2 += bf2f(g1[(size_t)(d0 + 2) * 64 + lane]);
    a3 += bf2f(g1[(size_t)(d0 + 3) * 64 + lane]);
    int w4 = w * 4;
    zs[w4 + 0][lane] = fmaxf(dv0 * a0 + b1v, 0.0f);
    zs[w4 + 1][lane] = fmaxf(dv1 * a1 + b1v, 0.0f);
    zs[w4 + 2][lane] = fmaxf(dv2 * a2 + b1v, 0.0f);
    zs[w4 + 3][lane] = fmaxf(dv3 * a3 + b1v, 0.0f);
    float c0 = 0.f, c1 = 0.f, c2 = 0.f, c3 = 0.f;
#pragma unroll 8
    for (int k = 0; k < HID_C; ++k) {
        float wv = W2[k * 64 + lane];
        c0 += zs[w4 + 0][k] * wv;
        c1 += zs[w4 + 1][k] * wv;
        c2 += zs[w4 + 2][k] * wv;
        c3 += zs[w4 + 3][k] * wv;
    }
    g2[(size_t)(d0 + 0) * 64 + lane] = f2bf(dv0 * c0);
    g2[(size_t)(d0 + 1) * 64 + lane] = f2bf(dv1 * c1);
    g2[(size_t)(d0 + 2) * 64 + lane] = f2bf(dv2 * c2);
    g2[(size_t)(d0 + 3) * 64 + lane] = f2bf(dv3 * c3);
}

// ---------------- K3: 4-row fused gather(g2)+bias -> decoder @Wd + bd -> out ----------------
__global__ __launch_bounds__(256) void fused2_kernel(const unsigned short* __restrict__ g2,
                                                     const int* __restrict__ csr,
                                                     const int* __restrict__ rowend,
                                                     const float* __restrict__ dinv,
                                                     const float* __restrict__ b2,
                                                     const float* __restrict__ Wd,
                                                     const float* __restrict__ bd,
                                                     float* __restrict__ out) {
    __shared__ float zs[16][64];
    int lane = threadIdx.x & 63;
    int w = threadIdx.x >> 6;
    int d0 = blockIdx.x * 16 + w * 4;
    int S  = __builtin_amdgcn_readfirstlane((d0 > 0) ? rowend[d0 - 1] : 0);
    int e0 = __builtin_amdgcn_readfirstlane(rowend[d0 + 0]);
    int e1 = __builtin_amdgcn_readfirstlane(rowend[d0 + 1]);
    int e2 = __builtin_amdgcn_readfirstlane(rowend[d0 + 2]);
    int e3 = __builtin_amdgcn_readfirstlane(rowend[d0 + 3]);
    float dv0 = dinv[d0 + 0], dv1 = dinv[d0 + 1], dv2 = dinv[d0 + 2], dv3 = dinv[d0 + 3];
    float b2v = b2[lane];
    float a0, a1, a2, a3;
    gather4(g2, csr, S, e0, e1, e2, e3, lane, a0, a1, a2, a3);
    a0 += bf2f(g2[(size_t)(d0 + 0) * 64 + lane]);
    a1 += bf2f(g2[(size_t)(d0 + 1) * 64 + lane]);
    a2 += bf2f(g2[(size_t)(d0 + 2) * 64 + lane]);
    a3 += bf2f(g2[(size_t)(d0 + 3) * 64 + lane]);
    int w4 = w * 4;
    zs[w4 + 0][lane] = dv0 * a0 + b2v;
    zs[w4 + 1][lane] = dv1 * a1 + b2v;
    zs[w4 + 2][lane] = dv2 * a2 + b2v;
    zs[w4 + 3][lane] = dv3 * a3 + b2v;
    float bdl = bd[lane], bdh = bd[64 + lane];
    float c0l = bdl, c0h = bdh, c1l = bdl, c1h = bdh;
    float c2l = bdl, c2h = bdh, c3l = bdl, c3h = bdh;
#pragma unroll 8
    for (int k = 0; k < OUT_C; ++k) {
        float w0 = Wd[k * 128 + lane];
        float w1 = Wd[k * 128 + 64 + lane];
        float z0 = zs[w4 + 0][k], z1 = zs[w4 + 1][k], z2 = zs[w4 + 2][k], z3 = zs[w4 + 3][k];
        c0l += z0 * w0; c0h += z0 * w1;
        c1l += z1 * w0; c1h += z1 * w1;
        c2l += z2 * w0; c2h += z2 * w1;
        c3l += z3 * w0; c3h += z3 * w1;
    }
    out[(size_t)(d0 + 0) * 128 + lane] = c0l; out[(size_t)(d0 + 0) * 128 + 64 + lane] = c0h;
    out[(size_t)(d0 + 1) * 128 + lane] = c1l; out[(size_t)(d0 + 1) * 128 + 64 + lane] = c1h;
    out[(size_t)(d0 + 2) * 128 + lane] = c2l; out[(size_t)(d0 + 2) * 128 + 64 + lane] = c2h;
    out[(size_t)(d0 + 3) * 128 + lane] = c3l; out[(size_t)(d0 + 3) * 128 + 64 + lane] = c3h;
}

extern "C" void kernel_launch(void* const* d_in, const int* in_sizes, int n_in,
                              void* d_out, int out_size, void* d_ws, size_t ws_size,
                              hipStream_t stream) {
    const float* x = (const float*)d_in[0];
    const int* ei = (const int*)d_in[1];  // int64 ref -> int32 from harness
    const int* src = ei;
    const int* dst = ei + E_EDGES;
    const float* W1 = (const float*)d_in[2];
    const float* b1 = (const float*)d_in[3];
    const float* W2 = (const float*)d_in[4];
    const float* b2 = (const float*)d_in[5];
    const float* Wd = (const float*)d_in[6];
    const float* bd = (const float*)d_in[7];
    float* out = (float*)d_out;

    // ws layout (4-byte units):
    // count[NPAD] | cursor[NPAD] | rowend[NPAD] | dinv[NPAD] | partial[512] | csr[PADMAX] | g2[(N+1)*64 bf16]
    int* count = (int*)d_ws;
    int* cursor = count + NPAD;
    int* rowend = cursor + NPAD;
    float* dinv = (float*)(rowend + NPAD);
    int* partial = (int*)(dinv + NPAD);
    int* csr = partial + 512;
    unsigned short* g2 = (unsigned short*)(csr + PADMAX);
    unsigned short* g1 = (unsigned short*)out;  // aliases d_out; dead before fused2 writes out

    const int B = 256;
    const int NB = (N_NODES + B - 1) / B;  // 391

    // ---- build padded CSR (by dst) + dinv ----
    zero_int_kernel<<<NB, B, 0, stream>>>(count, N_NODES);
    hist_kernel<<<E_EDGES / B, B, 0, stream>>>(dst, count, E_EDGES);
    scan1_kernel<<<NB, B, 0, stream>>>(count, partial, N_NODES);
    scan2_kernel<<<1, 64, 0, stream>>>(partial, NB, g1, g2);
    scan3_kernel<<<NB, B, 0, stream>>>(count, partial, cursor, rowend, dinv, N_NODES);
    fill_kernel<<<E_EDGES / B, B, 0, stream>>>(src, dst, cursor, csr, E_EDGES);
    pad_kernel<<<NB, B, 0, stream>>>(cursor, rowend, csr, N_NODES);

    // ---- layer 1 transform: g1 = bf16((x @ W1) * dinv) ----
    gemm1_kernel<<<N_NODES / 16, B, 0, stream>>>(x, W1, dinv, g1);
    // ---- fused: aggregate(g1) + b1 + relu, @W2, *dinv -> g2 ----
    fused1_kernel<<<N_NODES / 16, B, 0, stream>>>(g1, csr, rowend, dinv, b1, W2, g2);
    // ---- fused: aggregate(g2) + b2, decoder @Wd + bd -> out ----
    fused2_kernel<<<N_NODES / 16, B, 0, stream>>>(g2, csr, rowend, dinv, b2, Wd, bd, out);
}

// Round 7
// 280.760 us; speedup vs baseline: 4.1992x; 1.6179x over previous
//
#include <hip/hip_runtime.h>

constexpr int N_NODES = 100000;
constexpr int E_EDGES = 1600000;
constexpr int IN_C = 128, HID_C = 64, OUT_C = 64;
constexpr int NPAD = 100096;
constexpr int DUMMY = N_NODES;       // all-zero row in g tables
constexpr int BKT_SHIFT = 9;         // 512 nodes per bucket
constexpr int BKT_NODES = 512;
constexpr int NBKT = 196;            // ceil(100000/512)
constexpr int CSR_CAP = 16384;       // ints per bucket csr region (avg need ~10000)

// ---------------- bf16 helpers (RNE) ----------------
__device__ __forceinline__ unsigned short f2bf(float f) {
    unsigned int u = __float_as_uint(f);
    unsigned int r = (u + 0x7FFFu + ((u >> 16) & 1u)) >> 16;
    return (unsigned short)r;
}
__device__ __forceinline__ float bf2f(unsigned short b) {
    return __uint_as_float((unsigned int)b << 16);
}

// ---------------- P0: zero bucket histogram ----------------
__global__ void p0_zero(int* __restrict__ bhist) {
    if (threadIdx.x < NBKT) bhist[threadIdx.x] = 0;
}

// ---------------- P1a: coarse histogram (196 buckets) ----------------
__global__ __launch_bounds__(256) void p1a_hist(const int* __restrict__ dst,
                                                int* __restrict__ bhist, int E) {
    __shared__ int lc[NBKT];
    for (int i = threadIdx.x; i < NBKT; i += 256) lc[i] = 0;
    __syncthreads();
    int base = blockIdx.x * 4096;
    for (int k = 0; k < 16; ++k) {
        int i = base + k * 256 + threadIdx.x;
        if (i < E) atomicAdd(&lc[dst[i] >> BKT_SHIFT], 1);
    }
    __syncthreads();
    for (int i = threadIdx.x; i < NBKT; i += 256)
        if (lc[i]) atomicAdd(&bhist[i], lc[i]);
}

// ---------------- P1b: serial scan of 196 buckets; zero DUMMY rows ----------------
__global__ void p1b_scan(const int* __restrict__ bhist, int* __restrict__ ebase,
                         int* __restrict__ ecursor,
                         unsigned short* __restrict__ g1, unsigned short* __restrict__ g2) {
    if (threadIdx.x == 0) {
        int run = 0;
        for (int b = 0; b < NBKT; ++b) { ebase[b] = run; ecursor[b] = run; run += bhist[b]; }
    }
    unsigned int* r1 = (unsigned int*)(g1 + (size_t)N_NODES * 64);
    unsigned int* r2 = (unsigned int*)(g2 + (size_t)N_NODES * 64);
    if (threadIdx.x < 32) { r1[threadIdx.x] = 0u; r2[threadIdx.x] = 0u; }
}

// ---------------- P1c: place edges into coarse buckets (LDS-cursor, run-coalesced) ----------------
__global__ __launch_bounds__(256) void p1c_bin(const int* __restrict__ src,
                                               const int* __restrict__ dst,
                                               int* __restrict__ ecursor,
                                               uint2* __restrict__ bbuf, int E) {
    __shared__ int lc[NBKT], lbase[NBKT];
    for (int i = threadIdx.x; i < NBKT; i += 256) lc[i] = 0;
    __syncthreads();
    int base = blockIdx.x * 4096;
    int s[16], d[16];
    for (int k = 0; k < 16; ++k) {
        int i = base + k * 256 + threadIdx.x;
        s[k] = (i < E) ? src[i] : -1;
        d[k] = (i < E) ? dst[i] : -1;
        if (d[k] >= 0) atomicAdd(&lc[d[k] >> BKT_SHIFT], 1);
    }
    __syncthreads();
    for (int i = threadIdx.x; i < NBKT; i += 256) {
        int c = lc[i];
        lbase[i] = c ? atomicAdd(&ecursor[i], c) : 0;
        lc[i] = 0;
    }
    __syncthreads();
    for (int k = 0; k < 16; ++k) {
        if (d[k] >= 0) {
            int b = d[k] >> BKT_SHIFT;
            int pos = lbase[b] + atomicAdd(&lc[b], 1);
            bbuf[pos] = make_uint2((unsigned)s[k], (unsigned)d[k]);
        }
    }
}

// ---------------- P2: per-bucket fine CSR build + rowbeg/rowend/dinv + pad ----------------
__global__ __launch_bounds__(256) void p2_build(const uint2* __restrict__ bbuf,
                                                const int* __restrict__ ebase,
                                                const int* __restrict__ bhist,
                                                int* __restrict__ csr,
                                                int* __restrict__ rowbeg,
                                                int* __restrict__ rowend,
                                                float* __restrict__ dinv) {
    __shared__ int cnt[BKT_NODES];
    __shared__ int beg[BKT_NODES];
    __shared__ int cur[BKT_NODES];
    __shared__ int tsum[256];
    int b = blockIdx.x;
    int t = threadIdx.x;
    int e0 = ebase[b], ec = bhist[b];
    cnt[t] = 0; cnt[t + 256] = 0;
    __syncthreads();
    for (int i = t; i < ec; i += 256) {
        uint2 e = bbuf[e0 + i];
        atomicAdd(&cnt[e.y & (BKT_NODES - 1)], 1);
    }
    __syncthreads();
    int c0 = cnt[2 * t], c1 = cnt[2 * t + 1];
    int a0 = (c0 + 7) & ~7;
    int a1 = (c1 + 7) & ~7;
    tsum[t] = a0 + a1;
    __syncthreads();
    for (int off = 1; off < 256; off <<= 1) {
        int v = (t >= off) ? tsum[t - off] : 0;
        __syncthreads();
        tsum[t] += v;
        __syncthreads();
    }
    int excl = tsum[t] - (a0 + a1);
    int gb = b * CSR_CAP;
    beg[2 * t] = excl;
    beg[2 * t + 1] = excl + a0;
    cur[2 * t] = 0; cur[2 * t + 1] = 0;
    int n0 = b * BKT_NODES + 2 * t;
    if (n0 < N_NODES) {
        rowbeg[n0] = gb + excl; rowend[n0] = gb + excl + a0;
        dinv[n0] = rsqrtf((float)c0 + 1.0f);
    }
    if (n0 + 1 < N_NODES) {
        rowbeg[n0 + 1] = gb + excl + a0; rowend[n0 + 1] = gb + excl + a0 + a1;
        dinv[n0 + 1] = rsqrtf((float)c1 + 1.0f);
    }
    __syncthreads();
    for (int i = t; i < ec; i += 256) {
        uint2 e = bbuf[e0 + i];
        int ln = e.y & (BKT_NODES - 1);
        int pos = beg[ln] + atomicAdd(&cur[ln], 1);
        csr[gb + pos] = (int)e.x;
    }
    __syncthreads();
    // pad tails to 8-aligned with DUMMY
    {
        int p0 = beg[2 * t] + c0, p0e = beg[2 * t] + a0;
        for (int p = p0; p < p0e; ++p) csr[gb + p] = DUMMY;
        int p1 = beg[2 * t + 1] + c1, p1e = beg[2 * t + 1] + a1;
        for (int p = p1; p < p1e; ++p) csr[gb + p] = DUMMY;
    }
}

// ---------------- 4-row contiguous-span gather, 8-deep MLP, uniform routing ----------------
__device__ __forceinline__ void gather4(const unsigned short* __restrict__ g,
                                        const int* __restrict__ csr,
                                        int S, int e0, int e1, int e2, int e3, int lane,
                                        float& A0, float& A1, float& A2, float& A3) {
    float a0 = 0.f, a1 = 0.f, a2 = 0.f, a3 = 0.f;
    for (int base = S; base < e3; base += 64) {
        int m = min(64, e3 - base);            // multiple of 8 (rows are 8-aligned)
        int sv = (lane < m) ? csr[base + lane] : 0;
        for (int j = 0; j < m; j += 8) {
            int p = base + j;                  // uniform; whole 8-group in one row
            int s0 = __shfl(sv, j + 0), s1 = __shfl(sv, j + 1);
            int s2 = __shfl(sv, j + 2), s3 = __shfl(sv, j + 3);
            int s4 = __shfl(sv, j + 4), s5 = __shfl(sv, j + 5);
            int s6 = __shfl(sv, j + 6), s7 = __shfl(sv, j + 7);
            float f0 = bf2f(g[(size_t)s0 * 64 + lane]);
            float f1 = bf2f(g[(size_t)s1 * 64 + lane]);
            float f2 = bf2f(g[(size_t)s2 * 64 + lane]);
            float f3 = bf2f(g[(size_t)s3 * 64 + lane]);
            float f4 = bf2f(g[(size_t)s4 * 64 + lane]);
            float f5 = bf2f(g[(size_t)s5 * 64 + lane]);
            float f6 = bf2f(g[(size_t)s6 * 64 + lane]);
            float f7 = bf2f(g[(size_t)s7 * 64 + lane]);
            float tt = ((f0 + f1) + (f2 + f3)) + ((f4 + f5) + (f6 + f7));
            if (p < e1) { if (p < e0) a0 += tt; else a1 += tt; }
            else        { if (p < e2) a2 += tt; else a3 += tt; }
        }
    }
    A0 = a0; A1 = a1; A2 = a2; A3 = a3;
}

// ---------------- K1: g1 = bf16((x @ W1) * dinv[node]) ----------------
__global__ __launch_bounds__(256) void gemm1_kernel(const float* __restrict__ x,
                                                    const float* __restrict__ W1,
                                                    const float* __restrict__ dinv,
                                                    unsigned short* __restrict__ g1) {
    __shared__ float Wl[IN_C * HID_C];  // 32 KB
    for (int i = threadIdx.x; i < IN_C * HID_C; i += 256) Wl[i] = W1[i];
    __syncthreads();
    int c = threadIdx.x & 63;
    int g = threadIdx.x >> 6;
    int n0 = blockIdx.x * 16 + g * 4;
    const float* r0 = x + (size_t)n0 * IN_C;
    const float* r1 = r0 + IN_C;
    const float* r2 = r1 + IN_C;
    const float* r3 = r2 + IN_C;
    float a0 = 0.f, a1 = 0.f, a2 = 0.f, a3 = 0.f;
#pragma unroll
    for (int k = 0; k < IN_C; k += 4) {
        float4 x0 = *(const float4*)(r0 + k);
        float4 x1 = *(const float4*)(r1 + k);
        float4 x2 = *(const float4*)(r2 + k);
        float4 x3 = *(const float4*)(r3 + k);
        float w;
        w = Wl[(k + 0) * 64 + c]; a0 += x0.x * w; a1 += x1.x * w; a2 += x2.x * w; a3 += x3.x * w;
        w = Wl[(k + 1) * 64 + c]; a0 += x0.y * w; a1 += x1.y * w; a2 += x2.y * w; a3 += x3.y * w;
        w = Wl[(k + 2) * 64 + c]; a0 += x0.z * w; a1 += x1.z * w; a2 += x2.z * w; a3 += x3.z * w;
        w = Wl[(k + 3) * 64 + c]; a0 += x0.w * w; a1 += x1.w * w; a2 += x2.w * w; a3 += x3.w * w;
    }
    g1[(size_t)(n0 + 0) * 64 + c] = f2bf(a0 * dinv[n0 + 0]);
    g1[(size_t)(n0 + 1) * 64 + c] = f2bf(a1 * dinv[n0 + 1]);
    g1[(size_t)(n0 + 2) * 64 + c] = f2bf(a2 * dinv[n0 + 2]);
    g1[(size_t)(n0 + 3) * 64 + c] = f2bf(a3 * dinv[n0 + 3]);
}

// ---------------- K2: 4-row fused gather(g1)+bias+relu -> @W2 -> *dinv -> g2(bf16) ----------------
__global__ __launch_bounds__(256) void fused1_kernel(const unsigned short* __restrict__ g1,
                                                     const int* __restrict__ csr,
                                                     const int* __restrict__ rowbeg,
                                                     const int* __restrict__ rowend,
                                                     const float* __restrict__ dinv,
                                                     const float* __restrict__ b1,
                                                     const float* __restrict__ W2,
                                                     unsigned short* __restrict__ g2) {
    __shared__ float zs[16][64];
    int lane = threadIdx.x & 63;
    int w = threadIdx.x >> 6;
    int d0 = blockIdx.x * 16 + w * 4;
    int S  = __builtin_amdgcn_readfirstlane(rowbeg[d0]);
    int e0 = __builtin_amdgcn_readfirstlane(rowend[d0 + 0]);
    int e1 = __builtin_amdgcn_readfirstlane(rowend[d0 + 1]);
    int e2 = __builtin_amdgcn_readfirstlane(rowend[d0 + 2]);
    int e3 = __builtin_amdgcn_readfirstlane(rowend[d0 + 3]);
    float dv0 = dinv[d0 + 0], dv1 = dinv[d0 + 1], dv2 = dinv[d0 + 2], dv3 = dinv[d0 + 3];
    float b1v = b1[lane];
    float a0, a1, a2, a3;
    gather4(g1, csr, S, e0, e1, e2, e3, lane, a0, a1, a2, a3);
    a0 += bf2f(g1[(size_t)(d0 + 0) * 64 + lane]);
    a1 += bf2f(g1[(size_t)(d0 + 1) * 64 + lane]);
    a2 += bf2f(g1[(size_t)(d0 + 2) * 64 + lane]);
    a3 += bf2f(g1[(size_t)(d0 + 3) * 64 + lane]);
    int w4 = w * 4;
    zs[w4 + 0][lane] = fmaxf(dv0 * a0 + b1v, 0.0f);
    zs[w4 + 1][lane] = fmaxf(dv1 * a1 + b1v, 0.0f);
    zs[w4 + 2][lane] = fmaxf(dv2 * a2 + b1v, 0.0f);
    zs[w4 + 3][lane] = fmaxf(dv3 * a3 + b1v, 0.0f);
    float c0 = 0.f, c1 = 0.f, c2 = 0.f, c3 = 0.f;
#pragma unroll 8
    for (int k = 0; k < HID_C; ++k) {
        float wv = W2[k * 64 + lane];
        c0 += zs[w4 + 0][k] * wv;
        c1 += zs[w4 + 1][k] * wv;
        c2 += zs[w4 + 2][k] * wv;
        c3 += zs[w4 + 3][k] * wv;
    }
    g2[(size_t)(d0 + 0) * 64 + lane] = f2bf(dv0 * c0);
    g2[(size_t)(d0 + 1) * 64 + lane] = f2bf(dv1 * c1);
    g2[(size_t)(d0 + 2) * 64 + lane] = f2bf(dv2 * c2);
    g2[(size_t)(d0 + 3) * 64 + lane] = f2bf(dv3 * c3);
}

// ---------------- K3: 4-row fused gather(g2)+bias -> decoder @Wd + bd -> out ----------------
__global__ __launch_bounds__(256) void fused2_kernel(const unsigned short* __restrict__ g2,
                                                     const int* __restrict__ csr,
                                                     const int* __restrict__ rowbeg,
                                                     const int* __restrict__ rowend,
                                                     const float* __restrict__ dinv,
                                                     const float* __restrict__ b2,
                                                     const float* __restrict__ Wd,
                                                     const float* __restrict__ bd,
                                                     float* __restrict__ out) {
    __shared__ float zs[16][64];
    int lane = threadIdx.x & 63;
    int w = threadIdx.x >> 6;
    int d0 = blockIdx.x * 16 + w * 4;
    int S  = __builtin_amdgcn_readfirstlane(rowbeg[d0]);
    int e0 = __builtin_amdgcn_readfirstlane(rowend[d0 + 0]);
    int e1 = __builtin_amdgcn_readfirstlane(rowend[d0 + 1]);
    int e2 = __builtin_amdgcn_readfirstlane(rowend[d0 + 2]);
    int e3 = __builtin_amdgcn_readfirstlane(rowend[d0 + 3]);
    float dv0 = dinv[d0 + 0], dv1 = dinv[d0 + 1], dv2 = dinv[d0 + 2], dv3 = dinv[d0 + 3];
    float b2v = b2[lane];
    float a0, a1, a2, a3;
    gather4(g2, csr, S, e0, e1, e2, e3, lane, a0, a1, a2, a3);
    a0 += bf2f(g2[(size_t)(d0 + 0) * 64 + lane]);
    a1 += bf2f(g2[(size_t)(d0 + 1) * 64 + lane]);
    a2 += bf2f(g2[(size_t)(d0 + 2) * 64 + lane]);
    a3 += bf2f(g2[(size_t)(d0 + 3) * 64 + lane]);
    int w4 = w * 4;
    zs[w4 + 0][lane] = dv0 * a0 + b2v;
    zs[w4 + 1][lane] = dv1 * a1 + b2v;
    zs[w4 + 2][lane] = dv2 * a2 + b2v;
    zs[w4 + 3][lane] = dv3 * a3 + b2v;
    float bdl = bd[lane], bdh = bd[64 + lane];
    float c0l = bdl, c0h = bdh, c1l = bdl, c1h = bdh;
    float c2l = bdl, c2h = bdh, c3l = bdl, c3h = bdh;
#pragma unroll 8
    for (int k = 0; k < OUT_C; ++k) {
        float w0 = Wd[k * 128 + lane];
        float w1 = Wd[k * 128 + 64 + lane];
        float z0 = zs[w4 + 0][k], z1 = zs[w4 + 1][k], z2 = zs[w4 + 2][k], z3 = zs[w4 + 3][k];
        c0l += z0 * w0; c0h += z0 * w1;
        c1l += z1 * w0; c1h += z1 * w1;
        c2l += z2 * w0; c2h += z2 * w1;
        c3l += z3 * w0; c3h += z3 * w1;
    }
    out[(size_t)(d0 + 0) * 128 + lane] = c0l; out[(size_t)(d0 + 0) * 128 + 64 + lane] = c0h;
    out[(size_t)(d0 + 1) * 128 + lane] = c1l; out[(size_t)(d0 + 1) * 128 + 64 + lane] = c1h;
    out[(size_t)(d0 + 2) * 128 + lane] = c2l; out[(size_t)(d0 + 2) * 128 + 64 + lane] = c2h;
    out[(size_t)(d0 + 3) * 128 + lane] = c3l; out[(size_t)(d0 + 3) * 128 + 64 + lane] = c3h;
}

extern "C" void kernel_launch(void* const* d_in, const int* in_sizes, int n_in,
                              void* d_out, int out_size, void* d_ws, size_t ws_size,
                              hipStream_t stream) {
    const float* x = (const float*)d_in[0];
    const int* ei = (const int*)d_in[1];  // int64 ref -> int32 from harness
    const int* src = ei;
    const int* dst = ei + E_EDGES;
    const float* W1 = (const float*)d_in[2];
    const float* b1 = (const float*)d_in[3];
    const float* W2 = (const float*)d_in[4];
    const float* b2 = (const float*)d_in[5];
    const float* Wd = (const float*)d_in[6];
    const float* bd = (const float*)d_in[7];
    float* out = (float*)d_out;

    // ws layout (4-byte units):
    // bhist[256] | ebase[256] | ecursor[256] | rowbeg[NPAD] | rowend[NPAD] | dinv[NPAD]
    // | csr[NBKT*CSR_CAP] | g2[(N+1)*64 bf16]
    int* bhist = (int*)d_ws;
    int* ebase = bhist + 256;
    int* ecursor = ebase + 256;
    int* rowbeg = ecursor + 256;
    int* rowend = rowbeg + NPAD;
    float* dinv = (float*)(rowend + NPAD);
    int* csr = (int*)(dinv + NPAD);
    unsigned short* g2 = (unsigned short*)(csr + NBKT * CSR_CAP);
    // aliases into d_out (51.2 MB): g1 at [0, 12.8MB), bbuf at [16MB, 28.8MB)
    unsigned short* g1 = (unsigned short*)out;            // dead before fused2 writes out
    uint2* bbuf = (uint2*)((char*)d_out + 16000000);      // dead after p2_build

    const int B = 256;
    const int EB = (E_EDGES + 4095) / 4096;  // 391

    // ---- build bucketed CSR + rowbeg/rowend/dinv ----
    p0_zero<<<1, B, 0, stream>>>(bhist);
    p1a_hist<<<EB, B, 0, stream>>>(dst, bhist, E_EDGES);
    p1b_scan<<<1, 64, 0, stream>>>(bhist, ebase, ecursor, g1, g2);
    p1c_bin<<<EB, B, 0, stream>>>(src, dst, ecursor, bbuf, E_EDGES);
    p2_build<<<NBKT, B, 0, stream>>>(bbuf, ebase, bhist, csr, rowbeg, rowend, dinv);

    // ---- layer 1 transform: g1 = bf16((x @ W1) * dinv) ----
    gemm1_kernel<<<N_NODES / 16, B, 0, stream>>>(x, W1, dinv, g1);
    // ---- fused: aggregate(g1) + b1 + relu, @W2, *dinv -> g2 ----
    fused1_kernel<<<N_NODES / 16, B, 0, stream>>>(g1, csr, rowbeg, rowend, dinv, b1, W2, g2);
    // ---- fused: aggregate(g2) + b2, decoder @Wd + bd -> out ----
    fused2_kernel<<<N_NODES / 16, B, 0, stream>>>(g2, csr, rowbeg, rowend, dinv, b2, Wd, bd, out);
}

// Round 8
// 233.712 us; speedup vs baseline: 5.0445x; 1.2013x over previous
//
#include <hip/hip_runtime.h>

constexpr int N_NODES = 100000;
constexpr int E_EDGES = 1600000;
constexpr int IN_C = 128, HID_C = 64, OUT_C = 64;
constexpr int NPAD = 100096;
constexpr int DUMMY = N_NODES;       // all-zero row in g tables
constexpr int BKT_SHIFT = 9;         // 512 nodes per bucket
constexpr int BKT_NODES = 512;
constexpr int NBKT = 196;            // ceil(100000/512)
constexpr int CSR_CAP = 16384;       // ints per bucket csr region (avg need ~10000)

// ---------------- bf16 helpers (RNE) ----------------
__device__ __forceinline__ unsigned short f2bf(float f) {
    unsigned int u = __float_as_uint(f);
    unsigned int r = (u + 0x7FFFu + ((u >> 16) & 1u)) >> 16;
    return (unsigned short)r;
}
__device__ __forceinline__ float bf2f(unsigned short b) {
    return __uint_as_float((unsigned int)b << 16);
}

// ---------------- P0: zero bucket histogram ----------------
__global__ void p0_zero(int* __restrict__ bhist) {
    if (threadIdx.x < NBKT) bhist[threadIdx.x] = 0;
}

// ---------------- P1a: coarse histogram (196 buckets) ----------------
__global__ __launch_bounds__(256) void p1a_hist(const int* __restrict__ dst,
                                                int* __restrict__ bhist, int E) {
    __shared__ int lc[NBKT];
    for (int i = threadIdx.x; i < NBKT; i += 256) lc[i] = 0;
    __syncthreads();
    int base = blockIdx.x * 4096;
    for (int k = 0; k < 16; ++k) {
        int i = base + k * 256 + threadIdx.x;
        if (i < E) atomicAdd(&lc[dst[i] >> BKT_SHIFT], 1);
    }
    __syncthreads();
    for (int i = threadIdx.x; i < NBKT; i += 256)
        if (lc[i]) atomicAdd(&bhist[i], lc[i]);
}

// ---------------- P1b: serial scan of 196 buckets; zero DUMMY rows ----------------
__global__ void p1b_scan(const int* __restrict__ bhist, int* __restrict__ ebase,
                         int* __restrict__ ecursor,
                         unsigned short* __restrict__ g1, unsigned short* __restrict__ g2) {
    if (threadIdx.x == 0) {
        int run = 0;
        for (int b = 0; b < NBKT; ++b) { ebase[b] = run; ecursor[b] = run; run += bhist[b]; }
    }
    unsigned int* r1 = (unsigned int*)(g1 + (size_t)N_NODES * 64);
    unsigned int* r2 = (unsigned int*)(g2 + (size_t)N_NODES * 64);
    if (threadIdx.x < 32) { r1[threadIdx.x] = 0u; r2[threadIdx.x] = 0u; }
}

// ---------------- P1c: place edges into coarse buckets (LDS-cursor, run-coalesced) ----------------
__global__ __launch_bounds__(256) void p1c_bin(const int* __restrict__ src,
                                               const int* __restrict__ dst,
                                               int* __restrict__ ecursor,
                                               uint2* __restrict__ bbuf, int E) {
    __shared__ int lc[NBKT], lbase[NBKT];
    for (int i = threadIdx.x; i < NBKT; i += 256) lc[i] = 0;
    __syncthreads();
    int base = blockIdx.x * 4096;
    int s[16], d[16];
    for (int k = 0; k < 16; ++k) {
        int i = base + k * 256 + threadIdx.x;
        s[k] = (i < E) ? src[i] : -1;
        d[k] = (i < E) ? dst[i] : -1;
        if (d[k] >= 0) atomicAdd(&lc[d[k] >> BKT_SHIFT], 1);
    }
    __syncthreads();
    for (int i = threadIdx.x; i < NBKT; i += 256) {
        int c = lc[i];
        lbase[i] = c ? atomicAdd(&ecursor[i], c) : 0;
        lc[i] = 0;
    }
    __syncthreads();
    for (int k = 0; k < 16; ++k) {
        if (d[k] >= 0) {
            int b = d[k] >> BKT_SHIFT;
            int pos = lbase[b] + atomicAdd(&lc[b], 1);
            bbuf[pos] = make_uint2((unsigned)s[k], (unsigned)d[k]);
        }
    }
}

// ---------------- P2: per-bucket fine CSR build + rowbeg/rowend/dinv + pad ----------------
__global__ __launch_bounds__(256) void p2_build(const uint2* __restrict__ bbuf,
                                                const int* __restrict__ ebase,
                                                const int* __restrict__ bhist,
                                                int* __restrict__ csr,
                                                int* __restrict__ rowbeg,
                                                int* __restrict__ rowend,
                                                float* __restrict__ dinv) {
    __shared__ int cnt[BKT_NODES];
    __shared__ int beg[BKT_NODES];
    __shared__ int cur[BKT_NODES];
    __shared__ int tsum[256];
    int b = blockIdx.x;
    int t = threadIdx.x;
    int e0 = ebase[b], ec = bhist[b];
    cnt[t] = 0; cnt[t + 256] = 0;
    __syncthreads();
    for (int i = t; i < ec; i += 256) {
        uint2 e = bbuf[e0 + i];
        atomicAdd(&cnt[e.y & (BKT_NODES - 1)], 1);
    }
    __syncthreads();
    int c0 = cnt[2 * t], c1 = cnt[2 * t + 1];
    int a0 = (c0 + 7) & ~7;
    int a1 = (c1 + 7) & ~7;
    tsum[t] = a0 + a1;
    __syncthreads();
    for (int off = 1; off < 256; off <<= 1) {
        int v = (t >= off) ? tsum[t - off] : 0;
        __syncthreads();
        tsum[t] += v;
        __syncthreads();
    }
    int excl = tsum[t] - (a0 + a1);
    int gb = b * CSR_CAP;
    beg[2 * t] = excl;
    beg[2 * t + 1] = excl + a0;
    cur[2 * t] = 0; cur[2 * t + 1] = 0;
    int n0 = b * BKT_NODES + 2 * t;
    if (n0 < N_NODES) {
        rowbeg[n0] = gb + excl; rowend[n0] = gb + excl + a0;
        dinv[n0] = rsqrtf((float)c0 + 1.0f);
    }
    if (n0 + 1 < N_NODES) {
        rowbeg[n0 + 1] = gb + excl + a0; rowend[n0 + 1] = gb + excl + a0 + a1;
        dinv[n0 + 1] = rsqrtf((float)c1 + 1.0f);
    }
    __syncthreads();
    for (int i = t; i < ec; i += 256) {
        uint2 e = bbuf[e0 + i];
        int ln = e.y & (BKT_NODES - 1);
        int pos = beg[ln] + atomicAdd(&cur[ln], 1);
        csr[gb + pos] = (int)e.x;
    }
    __syncthreads();
    // pad tails to 8-aligned with DUMMY
    {
        int p0 = beg[2 * t] + c0, p0e = beg[2 * t] + a0;
        for (int p = p0; p < p0e; ++p) csr[gb + p] = DUMMY;
        int p1 = beg[2 * t + 1] + c1, p1e = beg[2 * t + 1] + a1;
        for (int p = p1; p < p1e; ++p) csr[gb + p] = DUMMY;
    }
}

// ---------------- 4-row contiguous-span gather, 8-deep MLP, uniform routing ----------------
__device__ __forceinline__ void gather4(const unsigned short* __restrict__ g,
                                        const int* __restrict__ csr,
                                        int S, int e0, int e1, int e2, int e3, int lane,
                                        float& A0, float& A1, float& A2, float& A3) {
    float a0 = 0.f, a1 = 0.f, a2 = 0.f, a3 = 0.f;
    for (int base = S; base < e3; base += 64) {
        int m = min(64, e3 - base);            // multiple of 8 (rows are 8-aligned)
        int sv = (lane < m) ? csr[base + lane] : 0;
        for (int j = 0; j < m; j += 8) {
            int p = base + j;                  // uniform; whole 8-group in one row
            int s0 = __shfl(sv, j + 0), s1 = __shfl(sv, j + 1);
            int s2 = __shfl(sv, j + 2), s3 = __shfl(sv, j + 3);
            int s4 = __shfl(sv, j + 4), s5 = __shfl(sv, j + 5);
            int s6 = __shfl(sv, j + 6), s7 = __shfl(sv, j + 7);
            float f0 = bf2f(g[(size_t)s0 * 64 + lane]);
            float f1 = bf2f(g[(size_t)s1 * 64 + lane]);
            float f2 = bf2f(g[(size_t)s2 * 64 + lane]);
            float f3 = bf2f(g[(size_t)s3 * 64 + lane]);
            float f4 = bf2f(g[(size_t)s4 * 64 + lane]);
            float f5 = bf2f(g[(size_t)s5 * 64 + lane]);
            float f6 = bf2f(g[(size_t)s6 * 64 + lane]);
            float f7 = bf2f(g[(size_t)s7 * 64 + lane]);
            float tt = ((f0 + f1) + (f2 + f3)) + ((f4 + f5) + (f6 + f7));
            if (p < e1) { if (p < e0) a0 += tt; else a1 += tt; }
            else        { if (p < e2) a2 += tt; else a3 += tt; }
        }
    }
    A0 = a0; A1 = a1; A2 = a2; A3 = a3;
}

// ---------------- K1: tiled GEMM g1 = bf16((x @ W1) * dinv) ----------------
// block = 64 nodes x 64 cols; x tile staged in LDS (32 KB), W1 from L1.
__global__ __launch_bounds__(256) void gemm1_kernel(const float* __restrict__ x,
                                                    const float* __restrict__ W1,
                                                    const float* __restrict__ dinv,
                                                    unsigned short* __restrict__ g1) {
    __shared__ float xs[64][IN_C];  // 32 KB
    int n0 = blockIdx.x * 64;
    // cooperative coalesced load of 64 x IN_C tile (2048 float4, 8 per thread)
    const float4* xv = (const float4*)(x + (size_t)n0 * IN_C);
    int maxv = (min(64, N_NODES - n0)) * (IN_C / 4);
    for (int i = threadIdx.x; i < 64 * (IN_C / 4); i += 256) {
        float4 v = (i < maxv) ? xv[i] : make_float4(0.f, 0.f, 0.f, 0.f);
        *(float4*)&xs[i >> 5][(i & 31) * 4] = v;
    }
    __syncthreads();
    int c = threadIdx.x & 63;
    int ng = threadIdx.x >> 6;  // 0..3 -> nodes ng*16 .. ng*16+15
    float acc[16];
#pragma unroll
    for (int i = 0; i < 16; ++i) acc[i] = 0.f;
    for (int k = 0; k < IN_C; k += 4) {
        float w0 = W1[(k + 0) * 64 + c];
        float w1 = W1[(k + 1) * 64 + c];
        float w2 = W1[(k + 2) * 64 + c];
        float w3 = W1[(k + 3) * 64 + c];
#pragma unroll
        for (int i = 0; i < 16; ++i) {
            float4 xv4 = *(const float4*)&xs[ng * 16 + i][k];  // same-addr broadcast
            acc[i] += xv4.x * w0 + xv4.y * w1 + xv4.z * w2 + xv4.w * w3;
        }
    }
#pragma unroll
    for (int i = 0; i < 16; ++i) {
        int n = n0 + ng * 16 + i;
        if (n < N_NODES) g1[(size_t)n * 64 + c] = f2bf(acc[i] * dinv[n]);
    }
}

// ---------------- K2: 4-row fused gather(g1)+bias+relu -> @W2 -> *dinv -> g2(bf16) ----------------
__global__ __launch_bounds__(256) void fused1_kernel(const unsigned short* __restrict__ g1,
                                                     const int* __restrict__ csr,
                                                     const int* __restrict__ rowbeg,
                                                     const int* __restrict__ rowend,
                                                     const float* __restrict__ dinv,
                                                     const float* __restrict__ b1,
                                                     const float* __restrict__ W2,
                                                     unsigned short* __restrict__ g2) {
    __shared__ float zs[16][64];
    int lane = threadIdx.x & 63;
    int w = threadIdx.x >> 6;
    int d0 = blockIdx.x * 16 + w * 4;
    int S  = __builtin_amdgcn_readfirstlane(rowbeg[d0]);
    int e0 = __builtin_amdgcn_readfirstlane(rowend[d0 + 0]);
    int e1 = __builtin_amdgcn_readfirstlane(rowend[d0 + 1]);
    int e2 = __builtin_amdgcn_readfirstlane(rowend[d0 + 2]);
    int e3 = __builtin_amdgcn_readfirstlane(rowend[d0 + 3]);
    float dv0 = dinv[d0 + 0], dv1 = dinv[d0 + 1], dv2 = dinv[d0 + 2], dv3 = dinv[d0 + 3];
    float b1v = b1[lane];
    float a0, a1, a2, a3;
    gather4(g1, csr, S, e0, e1, e2, e3, lane, a0, a1, a2, a3);
    a0 += bf2f(g1[(size_t)(d0 + 0) * 64 + lane]);
    a1 += bf2f(g1[(size_t)(d0 + 1) * 64 + lane]);
    a2 += bf2f(g1[(size_t)(d0 + 2) * 64 + lane]);
    a3 += bf2f(g1[(size_t)(d0 + 3) * 64 + lane]);
    int w4 = w * 4;
    zs[w4 + 0][lane] = fmaxf(dv0 * a0 + b1v, 0.0f);
    zs[w4 + 1][lane] = fmaxf(dv1 * a1 + b1v, 0.0f);
    zs[w4 + 2][lane] = fmaxf(dv2 * a2 + b1v, 0.0f);
    zs[w4 + 3][lane] = fmaxf(dv3 * a3 + b1v, 0.0f);
    float c0 = 0.f, c1 = 0.f, c2 = 0.f, c3 = 0.f;
#pragma unroll 8
    for (int k = 0; k < HID_C; ++k) {
        float wv = W2[k * 64 + lane];
        c0 += zs[w4 + 0][k] * wv;
        c1 += zs[w4 + 1][k] * wv;
        c2 += zs[w4 + 2][k] * wv;
        c3 += zs[w4 + 3][k] * wv;
    }
    g2[(size_t)(d0 + 0) * 64 + lane] = f2bf(dv0 * c0);
    g2[(size_t)(d0 + 1) * 64 + lane] = f2bf(dv1 * c1);
    g2[(size_t)(d0 + 2) * 64 + lane] = f2bf(dv2 * c2);
    g2[(size_t)(d0 + 3) * 64 + lane] = f2bf(dv3 * c3);
}

// ---------------- K3: 4-row fused gather(g2)+bias -> decoder @Wd + bd -> out ----------------
__global__ __launch_bounds__(256) void fused2_kernel(const unsigned short* __restrict__ g2,
                                                     const int* __restrict__ csr,
                                                     const int* __restrict__ rowbeg,
                                                     const int* __restrict__ rowend,
                                                     const float* __restrict__ dinv,
                                                     const float* __restrict__ b2,
                                                     const float* __restrict__ Wd,
                                                     const float* __restrict__ bd,
                                                     float* __restrict__ out) {
    __shared__ float zs[16][64];
    int lane = threadIdx.x & 63;
    int w = threadIdx.x >> 6;
    int d0 = blockIdx.x * 16 + w * 4;
    int S  = __builtin_amdgcn_readfirstlane(rowbeg[d0]);
    int e0 = __builtin_amdgcn_readfirstlane(rowend[d0 + 0]);
    int e1 = __builtin_amdgcn_readfirstlane(rowend[d0 + 1]);
    int e2 = __builtin_amdgcn_readfirstlane(rowend[d0 + 2]);
    int e3 = __builtin_amdgcn_readfirstlane(rowend[d0 + 3]);
    float dv0 = dinv[d0 + 0], dv1 = dinv[d0 + 1], dv2 = dinv[d0 + 2], dv3 = dinv[d0 + 3];
    float b2v = b2[lane];
    float a0, a1, a2, a3;
    gather4(g2, csr, S, e0, e1, e2, e3, lane, a0, a1, a2, a3);
    a0 += bf2f(g2[(size_t)(d0 + 0) * 64 + lane]);
    a1 += bf2f(g2[(size_t)(d0 + 1) * 64 + lane]);
    a2 += bf2f(g2[(size_t)(d0 + 2) * 64 + lane]);
    a3 += bf2f(g2[(size_t)(d0 + 3) * 64 + lane]);
    int w4 = w * 4;
    zs[w4 + 0][lane] = dv0 * a0 + b2v;
    zs[w4 + 1][lane] = dv1 * a1 + b2v;
    zs[w4 + 2][lane] = dv2 * a2 + b2v;
    zs[w4 + 3][lane] = dv3 * a3 + b2v;
    float bdl = bd[lane], bdh = bd[64 + lane];
    float c0l = bdl, c0h = bdh, c1l = bdl, c1h = bdh;
    float c2l = bdl, c2h = bdh, c3l = bdl, c3h = bdh;
#pragma unroll 8
    for (int k = 0; k < OUT_C; ++k) {
        float w0 = Wd[k * 128 + lane];
        float w1 = Wd[k * 128 + 64 + lane];
        float z0 = zs[w4 + 0][k], z1 = zs[w4 + 1][k], z2 = zs[w4 + 2][k], z3 = zs[w4 + 3][k];
        c0l += z0 * w0; c0h += z0 * w1;
        c1l += z1 * w0; c1h += z1 * w1;
        c2l += z2 * w0; c2h += z2 * w1;
        c3l += z3 * w0; c3h += z3 * w1;
    }
    out[(size_t)(d0 + 0) * 128 + lane] = c0l; out[(size_t)(d0 + 0) * 128 + 64 + lane] = c0h;
    out[(size_t)(d0 + 1) * 128 + lane] = c1l; out[(size_t)(d0 + 1) * 128 + 64 + lane] = c1h;
    out[(size_t)(d0 + 2) * 128 + lane] = c2l; out[(size_t)(d0 + 2) * 128 + 64 + lane] = c2h;
    out[(size_t)(d0 + 3) * 128 + lane] = c3l; out[(size_t)(d0 + 3) * 128 + 64 + lane] = c3h;
}

extern "C" void kernel_launch(void* const* d_in, const int* in_sizes, int n_in,
                              void* d_out, int out_size, void* d_ws, size_t ws_size,
                              hipStream_t stream) {
    const float* x = (const float*)d_in[0];
    const int* ei = (const int*)d_in[1];  // int64 ref -> int32 from harness
    const int* src = ei;
    const int* dst = ei + E_EDGES;
    const float* W1 = (const float*)d_in[2];
    const float* b1 = (const float*)d_in[3];
    const float* W2 = (const float*)d_in[4];
    const float* b2 = (const float*)d_in[5];
    const float* Wd = (const float*)d_in[6];
    const float* bd = (const float*)d_in[7];
    float* out = (float*)d_out;

    // ws layout (4-byte units):
    // bhist[256] | ebase[256] | ecursor[256] | rowbeg[NPAD] | rowend[NPAD] | dinv[NPAD]
    // | csr[NBKT*CSR_CAP] | g2[(N+1)*64 bf16]
    int* bhist = (int*)d_ws;
    int* ebase = bhist + 256;
    int* ecursor = ebase + 256;
    int* rowbeg = ecursor + 256;
    int* rowend = rowbeg + NPAD;
    float* dinv = (float*)(rowend + NPAD);
    int* csr = (int*)(dinv + NPAD);
    unsigned short* g2 = (unsigned short*)(csr + NBKT * CSR_CAP);
    // aliases into d_out (51.2 MB): g1 at [0, 12.8MB), bbuf at [16MB, 28.8MB)
    unsigned short* g1 = (unsigned short*)out;            // dead before fused2 writes out
    uint2* bbuf = (uint2*)((char*)d_out + 16000000);      // dead after p2_build

    const int B = 256;
    const int EB = (E_EDGES + 4095) / 4096;  // 391

    // ---- build bucketed CSR + rowbeg/rowend/dinv ----
    p0_zero<<<1, B, 0, stream>>>(bhist);
    p1a_hist<<<EB, B, 0, stream>>>(dst, bhist, E_EDGES);
    p1b_scan<<<1, 64, 0, stream>>>(bhist, ebase, ecursor, g1, g2);
    p1c_bin<<<EB, B, 0, stream>>>(src, dst, ecursor, bbuf, E_EDGES);
    p2_build<<<NBKT, B, 0, stream>>>(bbuf, ebase, bhist, csr, rowbeg, rowend, dinv);

    // ---- layer 1 transform: g1 = bf16((x @ W1) * dinv) ----
    gemm1_kernel<<<(N_NODES + 63) / 64, B, 0, stream>>>(x, W1, dinv, g1);
    // ---- fused: aggregate(g1) + b1 + relu, @W2, *dinv -> g2 ----
    fused1_kernel<<<N_NODES / 16, B, 0, stream>>>(g1, csr, rowbeg, rowend, dinv, b1, W2, g2);
    // ---- fused: aggregate(g2) + b2, decoder @Wd + bd -> out ----
    fused2_kernel<<<N_NODES / 16, B, 0, stream>>>(g2, csr, rowbeg, rowend, dinv, b2, Wd, bd, out);
}

// Round 9
// 222.377 us; speedup vs baseline: 5.3016x; 1.0510x over previous
//
#include <hip/hip_runtime.h>

constexpr int N_NODES = 100000;
constexpr int E_EDGES = 1600000;
constexpr int IN_C = 128, HID_C = 64, OUT_C = 64;
constexpr int NPAD = 100096;
constexpr int DUMMY = N_NODES;       // all-zero row in g tables
constexpr int BKT_SHIFT = 9;         // 512 nodes per bucket
constexpr int BKT_NODES = 512;
constexpr int NBKT = 196;            // ceil(100000/512)
constexpr int CSR_CAP = 16384;       // ints per bucket csr region (avg need ~10000)

// ---------------- bf16 helpers (RNE) ----------------
__device__ __forceinline__ unsigned short f2bf(float f) {
    unsigned int u = __float_as_uint(f);
    unsigned int r = (u + 0x7FFFu + ((u >> 16) & 1u)) >> 16;
    return (unsigned short)r;
}
__device__ __forceinline__ float bflo(unsigned int u) {   // low bf16 of packed pair
    return __uint_as_float(u << 16);
}
__device__ __forceinline__ float bfhi(unsigned int u) {   // high bf16 of packed pair
    return __uint_as_float(u & 0xFFFF0000u);
}

// ---------------- P0: zero bucket histogram ----------------
__global__ void p0_zero(int* __restrict__ bhist) {
    if (threadIdx.x < NBKT) bhist[threadIdx.x] = 0;
}

// ---------------- P1a: coarse histogram (196 buckets) ----------------
__global__ __launch_bounds__(256) void p1a_hist(const int* __restrict__ dst,
                                                int* __restrict__ bhist, int E) {
    __shared__ int lc[NBKT];
    for (int i = threadIdx.x; i < NBKT; i += 256) lc[i] = 0;
    __syncthreads();
    int base = blockIdx.x * 4096;
    for (int k = 0; k < 16; ++k) {
        int i = base + k * 256 + threadIdx.x;
        if (i < E) atomicAdd(&lc[dst[i] >> BKT_SHIFT], 1);
    }
    __syncthreads();
    for (int i = threadIdx.x; i < NBKT; i += 256)
        if (lc[i]) atomicAdd(&bhist[i], lc[i]);
}

// ---------------- P1b: serial scan of 196 buckets; zero DUMMY rows ----------------
__global__ void p1b_scan(const int* __restrict__ bhist, int* __restrict__ ebase,
                         int* __restrict__ ecursor,
                         unsigned short* __restrict__ g1, unsigned short* __restrict__ g2) {
    if (threadIdx.x == 0) {
        int run = 0;
        for (int b = 0; b < NBKT; ++b) { ebase[b] = run; ecursor[b] = run; run += bhist[b]; }
    }
    unsigned int* r1 = (unsigned int*)(g1 + (size_t)N_NODES * 64);
    unsigned int* r2 = (unsigned int*)(g2 + (size_t)N_NODES * 64);
    if (threadIdx.x < 32) { r1[threadIdx.x] = 0u; r2[threadIdx.x] = 0u; }
}

// ---------------- P1c: place edges into coarse buckets (packed src|dstLow) ----------------
__global__ __launch_bounds__(256) void p1c_bin(const int* __restrict__ src,
                                               const int* __restrict__ dst,
                                               int* __restrict__ ecursor,
                                               unsigned int* __restrict__ bbuf, int E) {
    __shared__ int lc[NBKT], lbase[NBKT];
    for (int i = threadIdx.x; i < NBKT; i += 256) lc[i] = 0;
    __syncthreads();
    int base = blockIdx.x * 4096;
    int s[16], d[16];
    for (int k = 0; k < 16; ++k) {
        int i = base + k * 256 + threadIdx.x;
        s[k] = (i < E) ? src[i] : -1;
        d[k] = (i < E) ? dst[i] : -1;
        if (d[k] >= 0) atomicAdd(&lc[d[k] >> BKT_SHIFT], 1);
    }
    __syncthreads();
    for (int i = threadIdx.x; i < NBKT; i += 256) {
        int c = lc[i];
        lbase[i] = c ? atomicAdd(&ecursor[i], c) : 0;
        lc[i] = 0;
    }
    __syncthreads();
    for (int k = 0; k < 16; ++k) {
        if (d[k] >= 0) {
            int b = d[k] >> BKT_SHIFT;
            int pos = lbase[b] + atomicAdd(&lc[b], 1);
            bbuf[pos] = (unsigned)s[k] | ((unsigned)(d[k] & (BKT_NODES - 1)) << 17);
        }
    }
}

// ---------------- P2: per-bucket fine CSR build + rowbeg/rowend/dinv + pad ----------------
__global__ __launch_bounds__(256) void p2_build(const unsigned int* __restrict__ bbuf,
                                                const int* __restrict__ ebase,
                                                const int* __restrict__ bhist,
                                                int* __restrict__ csr,
                                                int* __restrict__ rowbeg,
                                                int* __restrict__ rowend,
                                                float* __restrict__ dinv) {
    __shared__ int cnt[BKT_NODES];
    __shared__ int beg[BKT_NODES];
    __shared__ int cur[BKT_NODES];
    __shared__ int tsum[256];
    int b = blockIdx.x;
    int t = threadIdx.x;
    int e0 = ebase[b], ec = bhist[b];
    cnt[t] = 0; cnt[t + 256] = 0;
    __syncthreads();
    for (int i = t; i < ec; i += 256) {
        unsigned e = bbuf[e0 + i];
        atomicAdd(&cnt[e >> 17], 1);
    }
    __syncthreads();
    int c0 = cnt[2 * t], c1 = cnt[2 * t + 1];
    int a0 = (c0 + 7) & ~7;
    int a1 = (c1 + 7) & ~7;
    tsum[t] = a0 + a1;
    __syncthreads();
    for (int off = 1; off < 256; off <<= 1) {
        int v = (t >= off) ? tsum[t - off] : 0;
        __syncthreads();
        tsum[t] += v;
        __syncthreads();
    }
    int excl = tsum[t] - (a0 + a1);
    int gb = b * CSR_CAP;
    beg[2 * t] = excl;
    beg[2 * t + 1] = excl + a0;
    cur[2 * t] = 0; cur[2 * t + 1] = 0;
    int n0 = b * BKT_NODES + 2 * t;
    if (n0 < N_NODES) {
        rowbeg[n0] = gb + excl; rowend[n0] = gb + excl + a0;
        dinv[n0] = rsqrtf((float)c0 + 1.0f);
    }
    if (n0 + 1 < N_NODES) {
        rowbeg[n0 + 1] = gb + excl + a0; rowend[n0 + 1] = gb + excl + a0 + a1;
        dinv[n0 + 1] = rsqrtf((float)c1 + 1.0f);
    }
    __syncthreads();
    for (int i = t; i < ec; i += 256) {
        unsigned e = bbuf[e0 + i];
        int ln = e >> 17;
        int pos = beg[ln] + atomicAdd(&cur[ln], 1);
        csr[gb + pos] = (int)(e & 0x1FFFFu);
    }
    __syncthreads();
    // pad tails to 8-aligned with DUMMY
    {
        int p0 = beg[2 * t] + c0, p0e = beg[2 * t] + a0;
        for (int p = p0; p < p0e; ++p) csr[gb + p] = DUMMY;
        int p1 = beg[2 * t + 1] + c1, p1e = beg[2 * t + 1] + a1;
        for (int p = p1; p < p1e; ++p) csr[gb + p] = DUMMY;
    }
}

// ---------------- paired gather: 2 neighbors per wave-load ----------------
// lanes 0-31 take neighbors at even group offsets, lanes 32-63 odd offsets;
// each lane loads one packed uint = 2 bf16 channels (2*cp, 2*cp+1).
__device__ __forceinline__ void gather4(const unsigned short* __restrict__ g,
                                        const int* __restrict__ csr,
                                        int S, int e0, int e1, int e2, int e3, int lane,
                                        float2& A0, float2& A1, float2& A2, float2& A3) {
    const unsigned int* g32 = (const unsigned int*)g;
    int half = lane >> 5;
    int cp = lane & 31;
    float2 a0 = {0.f, 0.f}, a1 = {0.f, 0.f}, a2 = {0.f, 0.f}, a3 = {0.f, 0.f};
    for (int base = S; base < e3; base += 64) {
        int m = min(64, e3 - base);            // multiple of 8
        int sv = (lane < m) ? csr[base + lane] : 0;
        for (int j = 0; j < m; j += 8) {
            int p = base + j;                  // uniform: whole 8-group in one row
            int s0 = __shfl(sv, j + 0 + half);
            int s1 = __shfl(sv, j + 2 + half);
            int s2 = __shfl(sv, j + 4 + half);
            int s3 = __shfl(sv, j + 6 + half);
            unsigned u0 = g32[(size_t)s0 * 32 + cp];
            unsigned u1 = g32[(size_t)s1 * 32 + cp];
            unsigned u2 = g32[(size_t)s2 * 32 + cp];
            unsigned u3 = g32[(size_t)s3 * 32 + cp];
            float tx = (bflo(u0) + bflo(u1)) + (bflo(u2) + bflo(u3));
            float ty = (bfhi(u0) + bfhi(u1)) + (bfhi(u2) + bfhi(u3));
            if (p < e1) {
                if (p < e0) { a0.x += tx; a0.y += ty; } else { a1.x += tx; a1.y += ty; }
            } else {
                if (p < e2) { a2.x += tx; a2.y += ty; } else { a3.x += tx; a3.y += ty; }
            }
        }
    }
    // cross-half reduce: combine even-offset (lanes<32) and odd-offset (lanes>=32) partials
    a0.x += __shfl_xor(a0.x, 32); a0.y += __shfl_xor(a0.y, 32);
    a1.x += __shfl_xor(a1.x, 32); a1.y += __shfl_xor(a1.y, 32);
    a2.x += __shfl_xor(a2.x, 32); a2.y += __shfl_xor(a2.y, 32);
    a3.x += __shfl_xor(a3.x, 32); a3.y += __shfl_xor(a3.y, 32);
    A0 = a0; A1 = a1; A2 = a2; A3 = a3;
}

// ---------------- K1: tiled GEMM g1 = bf16((x @ W1) * dinv) ----------------
__global__ __launch_bounds__(256) void gemm1_kernel(const float* __restrict__ x,
                                                    const float* __restrict__ W1,
                                                    const float* __restrict__ dinv,
                                                    unsigned short* __restrict__ g1) {
    __shared__ float xs[64][IN_C];  // 32 KB
    int n0 = blockIdx.x * 64;
    const float4* xv = (const float4*)(x + (size_t)n0 * IN_C);
    int maxv = (min(64, N_NODES - n0)) * (IN_C / 4);
    for (int i = threadIdx.x; i < 64 * (IN_C / 4); i += 256) {
        float4 v = (i < maxv) ? xv[i] : make_float4(0.f, 0.f, 0.f, 0.f);
        *(float4*)&xs[i >> 5][(i & 31) * 4] = v;
    }
    __syncthreads();
    int c = threadIdx.x & 63;
    int ng = threadIdx.x >> 6;
    float acc[16];
#pragma unroll
    for (int i = 0; i < 16; ++i) acc[i] = 0.f;
    for (int k = 0; k < IN_C; k += 4) {
        float w0 = W1[(k + 0) * 64 + c];
        float w1 = W1[(k + 1) * 64 + c];
        float w2 = W1[(k + 2) * 64 + c];
        float w3 = W1[(k + 3) * 64 + c];
#pragma unroll
        for (int i = 0; i < 16; ++i) {
            float4 xv4 = *(const float4*)&xs[ng * 16 + i][k];
            acc[i] += xv4.x * w0 + xv4.y * w1 + xv4.z * w2 + xv4.w * w3;
        }
    }
#pragma unroll
    for (int i = 0; i < 16; ++i) {
        int n = n0 + ng * 16 + i;
        if (n < N_NODES) g1[(size_t)n * 64 + c] = f2bf(acc[i] * dinv[n]);
    }
}

// ---------------- K2: 4-row fused gather(g1)+bias+relu -> @W2 -> *dinv -> g2(bf16) ----------------
__global__ __launch_bounds__(256) void fused1_kernel(const unsigned short* __restrict__ g1,
                                                     const int* __restrict__ csr,
                                                     const int* __restrict__ rowbeg,
                                                     const int* __restrict__ rowend,
                                                     const float* __restrict__ dinv,
                                                     const float* __restrict__ b1,
                                                     const float* __restrict__ W2,
                                                     unsigned short* __restrict__ g2) {
    __shared__ float zs[16][64];
    int lane = threadIdx.x & 63;
    int w = threadIdx.x >> 6;
    int cp = lane & 31;
    int d0 = blockIdx.x * 16 + w * 4;
    int S  = __builtin_amdgcn_readfirstlane(rowbeg[d0]);
    int e0 = __builtin_amdgcn_readfirstlane(rowend[d0 + 0]);
    int e1 = __builtin_amdgcn_readfirstlane(rowend[d0 + 1]);
    int e2 = __builtin_amdgcn_readfirstlane(rowend[d0 + 2]);
    int e3 = __builtin_amdgcn_readfirstlane(rowend[d0 + 3]);
    float dv0 = dinv[d0 + 0], dv1 = dinv[d0 + 1], dv2 = dinv[d0 + 2], dv3 = dinv[d0 + 3];
    float2 a0, a1, a2, a3;
    gather4(g1, csr, S, e0, e1, e2, e3, lane, a0, a1, a2, a3);
    // self-loop (g row d) + bias + relu, then stage z rows (channel pairs)
    const unsigned int* g32 = (const unsigned int*)g1;
    unsigned su0 = g32[(size_t)(d0 + 0) * 32 + cp];
    unsigned su1 = g32[(size_t)(d0 + 1) * 32 + cp];
    unsigned su2 = g32[(size_t)(d0 + 2) * 32 + cp];
    unsigned su3 = g32[(size_t)(d0 + 3) * 32 + cp];
    float2 b1v = *(const float2*)&b1[2 * cp];
    int w4 = w * 4;
    if (lane < 32) {
        float2 z0 = make_float2(fmaxf(dv0 * (a0.x + bflo(su0)) + b1v.x, 0.f),
                                fmaxf(dv0 * (a0.y + bfhi(su0)) + b1v.y, 0.f));
        float2 z1 = make_float2(fmaxf(dv1 * (a1.x + bflo(su1)) + b1v.x, 0.f),
                                fmaxf(dv1 * (a1.y + bfhi(su1)) + b1v.y, 0.f));
        float2 z2 = make_float2(fmaxf(dv2 * (a2.x + bflo(su2)) + b1v.x, 0.f),
                                fmaxf(dv2 * (a2.y + bfhi(su2)) + b1v.y, 0.f));
        float2 z3 = make_float2(fmaxf(dv3 * (a3.x + bflo(su3)) + b1v.x, 0.f),
                                fmaxf(dv3 * (a3.y + bfhi(su3)) + b1v.y, 0.f));
        *(float2*)&zs[w4 + 0][2 * cp] = z0;
        *(float2*)&zs[w4 + 1][2 * cp] = z1;
        *(float2*)&zs[w4 + 2][2 * cp] = z2;
        *(float2*)&zs[w4 + 3][2 * cp] = z3;
    }
    float c0 = 0.f, c1 = 0.f, c2 = 0.f, c3 = 0.f;
#pragma unroll 8
    for (int k = 0; k < HID_C; ++k) {
        float wv = W2[k * 64 + lane];
        c0 += zs[w4 + 0][k] * wv;
        c1 += zs[w4 + 1][k] * wv;
        c2 += zs[w4 + 2][k] * wv;
        c3 += zs[w4 + 3][k] * wv;
    }
    g2[(size_t)(d0 + 0) * 64 + lane] = f2bf(dv0 * c0);
    g2[(size_t)(d0 + 1) * 64 + lane] = f2bf(dv1 * c1);
    g2[(size_t)(d0 + 2) * 64 + lane] = f2bf(dv2 * c2);
    g2[(size_t)(d0 + 3) * 64 + lane] = f2bf(dv3 * c3);
}

// ---------------- K3: 4-row fused gather(g2)+bias -> decoder @Wd + bd -> out ----------------
__global__ __launch_bounds__(256) void fused2_kernel(const unsigned short* __restrict__ g2,
                                                     const int* __restrict__ csr,
                                                     const int* __restrict__ rowbeg,
                                                     const int* __restrict__ rowend,
                                                     const float* __restrict__ dinv,
                                                     const float* __restrict__ b2,
                                                     const float* __restrict__ Wd,
                                                     const float* __restrict__ bd,
                                                     float* __restrict__ out) {
    __shared__ float zs[16][64];
    int lane = threadIdx.x & 63;
    int w = threadIdx.x >> 6;
    int cp = lane & 31;
    int d0 = blockIdx.x * 16 + w * 4;
    int S  = __builtin_amdgcn_readfirstlane(rowbeg[d0]);
    int e0 = __builtin_amdgcn_readfirstlane(rowend[d0 + 0]);
    int e1 = __builtin_amdgcn_readfirstlane(rowend[d0 + 1]);
    int e2 = __builtin_amdgcn_readfirstlane(rowend[d0 + 2]);
    int e3 = __builtin_amdgcn_readfirstlane(rowend[d0 + 3]);
    float dv0 = dinv[d0 + 0], dv1 = dinv[d0 + 1], dv2 = dinv[d0 + 2], dv3 = dinv[d0 + 3];
    float2 a0, a1, a2, a3;
    gather4(g2, csr, S, e0, e1, e2, e3, lane, a0, a1, a2, a3);
    const unsigned int* g32 = (const unsigned int*)g2;
    unsigned su0 = g32[(size_t)(d0 + 0) * 32 + cp];
    unsigned su1 = g32[(size_t)(d0 + 1) * 32 + cp];
    unsigned su2 = g32[(size_t)(d0 + 2) * 32 + cp];
    unsigned su3 = g32[(size_t)(d0 + 3) * 32 + cp];
    float2 b2v = *(const float2*)&b2[2 * cp];
    int w4 = w * 4;
    if (lane < 32) {
        float2 z0 = make_float2(dv0 * (a0.x + bflo(su0)) + b2v.x, dv0 * (a0.y + bfhi(su0)) + b2v.y);
        float2 z1 = make_float2(dv1 * (a1.x + bflo(su1)) + b2v.x, dv1 * (a1.y + bfhi(su1)) + b2v.y);
        float2 z2 = make_float2(dv2 * (a2.x + bflo(su2)) + b2v.x, dv2 * (a2.y + bfhi(su2)) + b2v.y);
        float2 z3 = make_float2(dv3 * (a3.x + bflo(su3)) + b2v.x, dv3 * (a3.y + bfhi(su3)) + b2v.y);
        *(float2*)&zs[w4 + 0][2 * cp] = z0;
        *(float2*)&zs[w4 + 1][2 * cp] = z1;
        *(float2*)&zs[w4 + 2][2 * cp] = z2;
        *(float2*)&zs[w4 + 3][2 * cp] = z3;
    }
    float bdl = bd[lane], bdh = bd[64 + lane];
    float c0l = bdl, c0h = bdh, c1l = bdl, c1h = bdh;
    float c2l = bdl, c2h = bdh, c3l = bdl, c3h = bdh;
#pragma unroll 8
    for (int k = 0; k < OUT_C; ++k) {
        float w0 = Wd[k * 128 + lane];
        float w1 = Wd[k * 128 + 64 + lane];
        float z0 = zs[w4 + 0][k], z1 = zs[w4 + 1][k], z2 = zs[w4 + 2][k], z3 = zs[w4 + 3][k];
        c0l += z0 * w0; c0h += z0 * w1;
        c1l += z1 * w0; c1h += z1 * w1;
        c2l += z2 * w0; c2h += z2 * w1;
        c3l += z3 * w0; c3h += z3 * w1;
    }
    out[(size_t)(d0 + 0) * 128 + lane] = c0l; out[(size_t)(d0 + 0) * 128 + 64 + lane] = c0h;
    out[(size_t)(d0 + 1) * 128 + lane] = c1l; out[(size_t)(d0 + 1) * 128 + 64 + lane] = c1h;
    out[(size_t)(d0 + 2) * 128 + lane] = c2l; out[(size_t)(d0 + 2) * 128 + 64 + lane] = c2h;
    out[(size_t)(d0 + 3) * 128 + lane] = c3l; out[(size_t)(d0 + 3) * 128 + 64 + lane] = c3h;
}

extern "C" void kernel_launch(void* const* d_in, const int* in_sizes, int n_in,
                              void* d_out, int out_size, void* d_ws, size_t ws_size,
                              hipStream_t stream) {
    const float* x = (const float*)d_in[0];
    const int* ei = (const int*)d_in[1];  // int64 ref -> int32 from harness
    const int* src = ei;
    const int* dst = ei + E_EDGES;
    const float* W1 = (const float*)d_in[2];
    const float* b1 = (const float*)d_in[3];
    const float* W2 = (const float*)d_in[4];
    const float* b2 = (const float*)d_in[5];
    const float* Wd = (const float*)d_in[6];
    const float* bd = (const float*)d_in[7];
    float* out = (float*)d_out;

    // ws layout (4-byte units):
    // bhist[256] | ebase[256] | ecursor[256] | rowbeg[NPAD] | rowend[NPAD] | dinv[NPAD]
    // | csr[NBKT*CSR_CAP] | g2[(N+1)*64 bf16]
    int* bhist = (int*)d_ws;
    int* ebase = bhist + 256;
    int* ecursor = ebase + 256;
    int* rowbeg = ecursor + 256;
    int* rowend = rowbeg + NPAD;
    float* dinv = (float*)(rowend + NPAD);
    int* csr = (int*)(dinv + NPAD);
    unsigned short* g2 = (unsigned short*)(csr + NBKT * CSR_CAP);
    // aliases into d_out (51.2 MB): g1 at [0, 12.8MB), bbuf at [16MB, 22.4MB)
    unsigned short* g1 = (unsigned short*)out;            // dead before fused2 writes out
    unsigned int* bbuf = (unsigned int*)((char*)d_out + 16000000);  // dead after p2_build

    const int B = 256;
    const int EB = (E_EDGES + 4095) / 4096;  // 391

    // ---- build bucketed CSR + rowbeg/rowend/dinv ----
    p0_zero<<<1, B, 0, stream>>>(bhist);
    p1a_hist<<<EB, B, 0, stream>>>(dst, bhist, E_EDGES);
    p1b_scan<<<1, 64, 0, stream>>>(bhist, ebase, ecursor, g1, g2);
    p1c_bin<<<EB, B, 0, stream>>>(src, dst, ecursor, bbuf, E_EDGES);
    p2_build<<<NBKT, B, 0, stream>>>(bbuf, ebase, bhist, csr, rowbeg, rowend, dinv);

    // ---- layer 1 transform: g1 = bf16((x @ W1) * dinv) ----
    gemm1_kernel<<<(N_NODES + 63) / 64, B, 0, stream>>>(x, W1, dinv, g1);
    // ---- fused: aggregate(g1) + b1 + relu, @W2, *dinv -> g2 ----
    fused1_kernel<<<N_NODES / 16, B, 0, stream>>>(g1, csr, rowbeg, rowend, dinv, b1, W2, g2);
    // ---- fused: aggregate(g2) + b2, decoder @Wd + bd -> out ----
    fused2_kernel<<<N_NODES / 16, B, 0, stream>>>(g2, csr, rowbeg, rowend, dinv, b2, Wd, bd, out);
}

// Round 10
// 197.744 us; speedup vs baseline: 5.9621x; 1.1246x over previous
//
#include <hip/hip_runtime.h>

constexpr int N_NODES = 100000;
constexpr int E_EDGES = 1600000;
constexpr int IN_C = 128, HID_C = 64, OUT_C = 64;
constexpr int IN_CP = 132;           // padded LDS row (conflict-free 4-row b128 reads)
constexpr int NPAD = 100096;
constexpr int DUMMY = N_NODES;       // all-zero row in g tables
constexpr int BKT_SHIFT = 9;         // 512 nodes per bucket
constexpr int BKT_NODES = 512;
constexpr int NBKT = 196;            // ceil(100000/512)
constexpr int CSR_CAP = 16384;       // ints per bucket csr region
constexpr int CAPB = 16384;          // fixed bbuf slots per bucket (avg ~8192, std ~90)

// ---------------- bf16 helpers (RNE) ----------------
__device__ __forceinline__ unsigned short f2bf(float f) {
    unsigned int u = __float_as_uint(f);
    unsigned int r = (u + 0x7FFFu + ((u >> 16) & 1u)) >> 16;
    return (unsigned short)r;
}
__device__ __forceinline__ float bflo(unsigned int u) {
    return __uint_as_float(u << 16);
}
__device__ __forceinline__ float bfhi(unsigned int u) {
    return __uint_as_float(u & 0xFFFF0000u);
}

// ---------------- P0: zero bucket counters + DUMMY rows ----------------
__global__ void p0_zero(int* __restrict__ bcount,
                        unsigned short* __restrict__ g1, unsigned short* __restrict__ g2) {
    int t = threadIdx.x;
    if (t < NBKT) bcount[t] = 0;
    unsigned int* r1 = (unsigned int*)(g1 + (size_t)N_NODES * 64);
    unsigned int* r2 = (unsigned int*)(g2 + (size_t)N_NODES * 64);
    if (t < 64) { r1[t] = 0u; r2[t] = 0u; }
}

// ---------------- P1: place edges into fixed-capacity coarse buckets ----------------
__global__ __launch_bounds__(256) void p1c_bin(const int* __restrict__ src,
                                               const int* __restrict__ dst,
                                               int* __restrict__ bcount,
                                               unsigned int* __restrict__ bbuf, int E) {
    __shared__ int lc[NBKT], lbase[NBKT];
    for (int i = threadIdx.x; i < NBKT; i += 256) lc[i] = 0;
    __syncthreads();
    int base = blockIdx.x * 4096;
    int s[16], d[16];
    for (int k = 0; k < 16; ++k) {
        int i = base + k * 256 + threadIdx.x;
        s[k] = (i < E) ? src[i] : -1;
        d[k] = (i < E) ? dst[i] : -1;
        if (d[k] >= 0) atomicAdd(&lc[d[k] >> BKT_SHIFT], 1);
    }
    __syncthreads();
    for (int i = threadIdx.x; i < NBKT; i += 256) {
        int c = lc[i];
        lbase[i] = c ? (i * CAPB + atomicAdd(&bcount[i], c)) : 0;
        lc[i] = 0;
    }
    __syncthreads();
    for (int k = 0; k < 16; ++k) {
        if (d[k] >= 0) {
            int b = d[k] >> BKT_SHIFT;
            int pos = lbase[b] + atomicAdd(&lc[b], 1);
            bbuf[pos] = (unsigned)s[k] | ((unsigned)(d[k] & (BKT_NODES - 1)) << 17);
        }
    }
}

// ---------------- P2: per-bucket fine CSR build + rowbeg/rowend/dinv + pad ----------------
__global__ __launch_bounds__(256) void p2_build(const unsigned int* __restrict__ bbuf,
                                                const int* __restrict__ bcount,
                                                int* __restrict__ csr,
                                                int* __restrict__ rowbeg,
                                                int* __restrict__ rowend,
                                                float* __restrict__ dinv) {
    __shared__ int cnt[BKT_NODES];
    __shared__ int beg[BKT_NODES];
    __shared__ int cur[BKT_NODES];
    __shared__ int tsum[256];
    int b = blockIdx.x;
    int t = threadIdx.x;
    int e0 = b * CAPB, ec = bcount[b];
    cnt[t] = 0; cnt[t + 256] = 0;
    __syncthreads();
    for (int i = t; i < ec; i += 256) {
        unsigned e = bbuf[e0 + i];
        atomicAdd(&cnt[e >> 17], 1);
    }
    __syncthreads();
    int c0 = cnt[2 * t], c1 = cnt[2 * t + 1];
    int a0 = (c0 + 7) & ~7;
    int a1 = (c1 + 7) & ~7;
    tsum[t] = a0 + a1;
    __syncthreads();
    for (int off = 1; off < 256; off <<= 1) {
        int v = (t >= off) ? tsum[t - off] : 0;
        __syncthreads();
        tsum[t] += v;
        __syncthreads();
    }
    int excl = tsum[t] - (a0 + a1);
    int gb = b * CSR_CAP;
    beg[2 * t] = excl;
    beg[2 * t + 1] = excl + a0;
    cur[2 * t] = 0; cur[2 * t + 1] = 0;
    int n0 = b * BKT_NODES + 2 * t;
    if (n0 < N_NODES) {
        rowbeg[n0] = gb + excl; rowend[n0] = gb + excl + a0;
        dinv[n0] = rsqrtf((float)c0 + 1.0f);
    }
    if (n0 + 1 < N_NODES) {
        rowbeg[n0 + 1] = gb + excl + a0; rowend[n0 + 1] = gb + excl + a0 + a1;
        dinv[n0 + 1] = rsqrtf((float)c1 + 1.0f);
    }
    __syncthreads();
    for (int i = t; i < ec; i += 256) {
        unsigned e = bbuf[e0 + i];
        int ln = e >> 17;
        int pos = beg[ln] + atomicAdd(&cur[ln], 1);
        csr[gb + pos] = (int)(e & 0x1FFFFu);
    }
    __syncthreads();
    {
        int p0 = beg[2 * t] + c0, p0e = beg[2 * t] + a0;
        for (int p = p0; p < p0e; ++p) csr[gb + p] = DUMMY;
        int p1 = beg[2 * t + 1] + c1, p1e = beg[2 * t + 1] + a1;
        for (int p = p1; p < p1e; ++p) csr[gb + p] = DUMMY;
    }
}

// ---------------- paired gather: 2 neighbors per wave-load ----------------
__device__ __forceinline__ void gather4(const unsigned short* __restrict__ g,
                                        const int* __restrict__ csr,
                                        int S, int e0, int e1, int e2, int e3, int lane,
                                        float2& A0, float2& A1, float2& A2, float2& A3) {
    const unsigned int* g32 = (const unsigned int*)g;
    int half = lane >> 5;
    int cp = lane & 31;
    float2 a0 = {0.f, 0.f}, a1 = {0.f, 0.f}, a2 = {0.f, 0.f}, a3 = {0.f, 0.f};
    for (int base = S; base < e3; base += 64) {
        int m = min(64, e3 - base);            // multiple of 8
        int sv = (lane < m) ? csr[base + lane] : 0;
        for (int j = 0; j < m; j += 8) {
            int p = base + j;                  // uniform: whole 8-group in one row
            int s0 = __shfl(sv, j + 0 + half);
            int s1 = __shfl(sv, j + 2 + half);
            int s2 = __shfl(sv, j + 4 + half);
            int s3 = __shfl(sv, j + 6 + half);
            unsigned u0 = g32[(size_t)s0 * 32 + cp];
            unsigned u1 = g32[(size_t)s1 * 32 + cp];
            unsigned u2 = g32[(size_t)s2 * 32 + cp];
            unsigned u3 = g32[(size_t)s3 * 32 + cp];
            float tx = (bflo(u0) + bflo(u1)) + (bflo(u2) + bflo(u3));
            float ty = (bfhi(u0) + bfhi(u1)) + (bfhi(u2) + bfhi(u3));
            if (p < e1) {
                if (p < e0) { a0.x += tx; a0.y += ty; } else { a1.x += tx; a1.y += ty; }
            } else {
                if (p < e2) { a2.x += tx; a2.y += ty; } else { a3.x += tx; a3.y += ty; }
            }
        }
    }
    a0.x += __shfl_xor(a0.x, 32); a0.y += __shfl_xor(a0.y, 32);
    a1.x += __shfl_xor(a1.x, 32); a1.y += __shfl_xor(a1.y, 32);
    a2.x += __shfl_xor(a2.x, 32); a2.y += __shfl_xor(a2.y, 32);
    a3.x += __shfl_xor(a3.x, 32); a3.y += __shfl_xor(a3.y, 32);
    A0 = a0; A1 = a1; A2 = a2; A3 = a3;
}

// ---------------- K1: tiled GEMM g1 = bf16((x @ W1) * dinv), 4x4 register blocking ----------------
#define ROWOP(ACC, XR)                                                              \
    ACC[0] += XR.x * w0.x + XR.y * w1.x + XR.z * w2.x + XR.w * w3.x;                \
    ACC[1] += XR.x * w0.y + XR.y * w1.y + XR.z * w2.y + XR.w * w3.y;                \
    ACC[2] += XR.x * w0.z + XR.y * w1.z + XR.z * w2.z + XR.w * w3.z;                \
    ACC[3] += XR.x * w0.w + XR.y * w1.w + XR.z * w2.w + XR.w * w3.w;

__global__ __launch_bounds__(256) void gemm1_kernel(const float* __restrict__ x,
                                                    const float* __restrict__ W1,
                                                    const float* __restrict__ dinv,
                                                    unsigned short* __restrict__ g1) {
    __shared__ float xs[64][IN_CP];  // 33.8 KB, padded: rows r..r+3 hit disjoint bank groups
    int n0 = blockIdx.x * 64;
    const float4* xv = (const float4*)(x + (size_t)n0 * IN_C);
    int maxv = (min(64, N_NODES - n0)) * (IN_C / 4);
    for (int i = threadIdx.x; i < 64 * (IN_C / 4); i += 256) {
        float4 v = (i < maxv) ? xv[i] : make_float4(0.f, 0.f, 0.f, 0.f);
        *(float4*)&xs[i >> 5][(i & 31) * 4] = v;
    }
    __syncthreads();
    int cg = (threadIdx.x & 15) * 4;   // 4 cols
    int ng = (threadIdx.x >> 4) * 4;   // 4 nodes within tile
    float acc0[4] = {0.f, 0.f, 0.f, 0.f};
    float acc1[4] = {0.f, 0.f, 0.f, 0.f};
    float acc2[4] = {0.f, 0.f, 0.f, 0.f};
    float acc3[4] = {0.f, 0.f, 0.f, 0.f};
#pragma unroll 4
    for (int k = 0; k < IN_C; k += 4) {
        float4 xr0 = *(const float4*)&xs[ng + 0][k];
        float4 xr1 = *(const float4*)&xs[ng + 1][k];
        float4 xr2 = *(const float4*)&xs[ng + 2][k];
        float4 xr3 = *(const float4*)&xs[ng + 3][k];
        float4 w0 = *(const float4*)&W1[(k + 0) * 64 + cg];
        float4 w1 = *(const float4*)&W1[(k + 1) * 64 + cg];
        float4 w2 = *(const float4*)&W1[(k + 2) * 64 + cg];
        float4 w3 = *(const float4*)&W1[(k + 3) * 64 + cg];
        ROWOP(acc0, xr0)
        ROWOP(acc1, xr1)
        ROWOP(acc2, xr2)
        ROWOP(acc3, xr3)
    }
#pragma unroll
    for (int i = 0; i < 4; ++i) {
        int n = n0 + ng + i;
        if (n < N_NODES) {
            float dv = dinv[n];
            const float* a = (i == 0) ? acc0 : (i == 1) ? acc1 : (i == 2) ? acc2 : acc3;
            ushort4 o;
            o.x = f2bf(a[0] * dv);
            o.y = f2bf(a[1] * dv);
            o.z = f2bf(a[2] * dv);
            o.w = f2bf(a[3] * dv);
            *(ushort4*)&g1[(size_t)n * 64 + cg] = o;
        }
    }
}

// ---------------- K2: 4-row fused gather(g1)+bias+relu -> @W2 -> *dinv -> g2(bf16) ----------------
__global__ __launch_bounds__(256) void fused1_kernel(const unsigned short* __restrict__ g1,
                                                     const int* __restrict__ csr,
                                                     const int* __restrict__ rowbeg,
                                                     const int* __restrict__ rowend,
                                                     const float* __restrict__ dinv,
                                                     const float* __restrict__ b1,
                                                     const float* __restrict__ W2,
                                                     unsigned short* __restrict__ g2) {
    __shared__ float zs[16][64];
    int lane = threadIdx.x & 63;
    int w = threadIdx.x >> 6;
    int cp = lane & 31;
    int d0 = blockIdx.x * 16 + w * 4;
    int S  = __builtin_amdgcn_readfirstlane(rowbeg[d0]);
    int e0 = __builtin_amdgcn_readfirstlane(rowend[d0 + 0]);
    int e1 = __builtin_amdgcn_readfirstlane(rowend[d0 + 1]);
    int e2 = __builtin_amdgcn_readfirstlane(rowend[d0 + 2]);
    int e3 = __builtin_amdgcn_readfirstlane(rowend[d0 + 3]);
    float dv0 = dinv[d0 + 0], dv1 = dinv[d0 + 1], dv2 = dinv[d0 + 2], dv3 = dinv[d0 + 3];
    float2 a0, a1, a2, a3;
    gather4(g1, csr, S, e0, e1, e2, e3, lane, a0, a1, a2, a3);
    const unsigned int* g32 = (const unsigned int*)g1;
    unsigned su0 = g32[(size_t)(d0 + 0) * 32 + cp];
    unsigned su1 = g32[(size_t)(d0 + 1) * 32 + cp];
    unsigned su2 = g32[(size_t)(d0 + 2) * 32 + cp];
    unsigned su3 = g32[(size_t)(d0 + 3) * 32 + cp];
    float2 b1v = *(const float2*)&b1[2 * cp];
    int w4 = w * 4;
    if (lane < 32) {
        float2 z0 = make_float2(fmaxf(dv0 * (a0.x + bflo(su0)) + b1v.x, 0.f),
                                fmaxf(dv0 * (a0.y + bfhi(su0)) + b1v.y, 0.f));
        float2 z1 = make_float2(fmaxf(dv1 * (a1.x + bflo(su1)) + b1v.x, 0.f),
                                fmaxf(dv1 * (a1.y + bfhi(su1)) + b1v.y, 0.f));
        float2 z2 = make_float2(fmaxf(dv2 * (a2.x + bflo(su2)) + b1v.x, 0.f),
                                fmaxf(dv2 * (a2.y + bfhi(su2)) + b1v.y, 0.f));
        float2 z3 = make_float2(fmaxf(dv3 * (a3.x + bflo(su3)) + b1v.x, 0.f),
                                fmaxf(dv3 * (a3.y + bfhi(su3)) + b1v.y, 0.f));
        *(float2*)&zs[w4 + 0][2 * cp] = z0;
        *(float2*)&zs[w4 + 1][2 * cp] = z1;
        *(float2*)&zs[w4 + 2][2 * cp] = z2;
        *(float2*)&zs[w4 + 3][2 * cp] = z3;
    }
    float c0 = 0.f, c1 = 0.f, c2 = 0.f, c3 = 0.f;
#pragma unroll 8
    for (int k = 0; k < HID_C; ++k) {
        float wv = W2[k * 64 + lane];
        c0 += zs[w4 + 0][k] * wv;
        c1 += zs[w4 + 1][k] * wv;
        c2 += zs[w4 + 2][k] * wv;
        c3 += zs[w4 + 3][k] * wv;
    }
    g2[(size_t)(d0 + 0) * 64 + lane] = f2bf(dv0 * c0);
    g2[(size_t)(d0 + 1) * 64 + lane] = f2bf(dv1 * c1);
    g2[(size_t)(d0 + 2) * 64 + lane] = f2bf(dv2 * c2);
    g2[(size_t)(d0 + 3) * 64 + lane] = f2bf(dv3 * c3);
}

// ---------------- K3: 4-row fused gather(g2)+bias -> decoder @Wd + bd -> out ----------------
__global__ __launch_bounds__(256) void fused2_kernel(const unsigned short* __restrict__ g2,
                                                     const int* __restrict__ csr,
                                                     const int* __restrict__ rowbeg,
                                                     const int* __restrict__ rowend,
                                                     const float* __restrict__ dinv,
                                                     const float* __restrict__ b2,
                                                     const float* __restrict__ Wd,
                                                     const float* __restrict__ bd,
                                                     float* __restrict__ out) {
    __shared__ float zs[16][64];
    int lane = threadIdx.x & 63;
    int w = threadIdx.x >> 6;
    int cp = lane & 31;
    int d0 = blockIdx.x * 16 + w * 4;
    int S  = __builtin_amdgcn_readfirstlane(rowbeg[d0]);
    int e0 = __builtin_amdgcn_readfirstlane(rowend[d0 + 0]);
    int e1 = __builtin_amdgcn_readfirstlane(rowend[d0 + 1]);
    int e2 = __builtin_amdgcn_readfirstlane(rowend[d0 + 2]);
    int e3 = __builtin_amdgcn_readfirstlane(rowend[d0 + 3]);
    float dv0 = dinv[d0 + 0], dv1 = dinv[d0 + 1], dv2 = dinv[d0 + 2], dv3 = dinv[d0 + 3];
    float2 a0, a1, a2, a3;
    gather4(g2, csr, S, e0, e1, e2, e3, lane, a0, a1, a2, a3);
    const unsigned int* g32 = (const unsigned int*)g2;
    unsigned su0 = g32[(size_t)(d0 + 0) * 32 + cp];
    unsigned su1 = g32[(size_t)(d0 + 1) * 32 + cp];
    unsigned su2 = g32[(size_t)(d0 + 2) * 32 + cp];
    unsigned su3 = g32[(size_t)(d0 + 3) * 32 + cp];
    float2 b2v = *(const float2*)&b2[2 * cp];
    int w4 = w * 4;
    if (lane < 32) {
        float2 z0 = make_float2(dv0 * (a0.x + bflo(su0)) + b2v.x, dv0 * (a0.y + bfhi(su0)) + b2v.y);
        float2 z1 = make_float2(dv1 * (a1.x + bflo(su1)) + b2v.x, dv1 * (a1.y + bfhi(su1)) + b2v.y);
        float2 z2 = make_float2(dv2 * (a2.x + bflo(su2)) + b2v.x, dv2 * (a2.y + bfhi(su2)) + b2v.y);
        float2 z3 = make_float2(dv3 * (a3.x + bflo(su3)) + b2v.x, dv3 * (a3.y + bfhi(su3)) + b2v.y);
        *(float2*)&zs[w4 + 0][2 * cp] = z0;
        *(float2*)&zs[w4 + 1][2 * cp] = z1;
        *(float2*)&zs[w4 + 2][2 * cp] = z2;
        *(float2*)&zs[w4 + 3][2 * cp] = z3;
    }
    float bdl = bd[lane], bdh = bd[64 + lane];
    float c0l = bdl, c0h = bdh, c1l = bdl, c1h = bdh;
    float c2l = bdl, c2h = bdh, c3l = bdl, c3h = bdh;
#pragma unroll 8
    for (int k = 0; k < OUT_C; ++k) {
        float w0 = Wd[k * 128 + lane];
        float w1 = Wd[k * 128 + 64 + lane];
        float z0 = zs[w4 + 0][k], z1 = zs[w4 + 1][k], z2 = zs[w4 + 2][k], z3 = zs[w4 + 3][k];
        c0l += z0 * w0; c0h += z0 * w1;
        c1l += z1 * w0; c1h += z1 * w1;
        c2l += z2 * w0; c2h += z2 * w1;
        c3l += z3 * w0; c3h += z3 * w1;
    }
    out[(size_t)(d0 + 0) * 128 + lane] = c0l; out[(size_t)(d0 + 0) * 128 + 64 + lane] = c0h;
    out[(size_t)(d0 + 1) * 128 + lane] = c1l; out[(size_t)(d0 + 1) * 128 + 64 + lane] = c1h;
    out[(size_t)(d0 + 2) * 128 + lane] = c2l; out[(size_t)(d0 + 2) * 128 + 64 + lane] = c2h;
    out[(size_t)(d0 + 3) * 128 + lane] = c3l; out[(size_t)(d0 + 3) * 128 + 64 + lane] = c3h;
}

extern "C" void kernel_launch(void* const* d_in, const int* in_sizes, int n_in,
                              void* d_out, int out_size, void* d_ws, size_t ws_size,
                              hipStream_t stream) {
    const float* x = (const float*)d_in[0];
    const int* ei = (const int*)d_in[1];  // int64 ref -> int32 from harness
    const int* src = ei;
    const int* dst = ei + E_EDGES;
    const float* W1 = (const float*)d_in[2];
    const float* b1 = (const float*)d_in[3];
    const float* W2 = (const float*)d_in[4];
    const float* b2 = (const float*)d_in[5];
    const float* Wd = (const float*)d_in[6];
    const float* bd = (const float*)d_in[7];
    float* out = (float*)d_out;

    // ws layout (4-byte units):
    // bcount[256] | rowbeg[NPAD] | rowend[NPAD] | dinv[NPAD] | csr[NBKT*CSR_CAP] | g2[(N+1)*64 bf16]
    int* bcount = (int*)d_ws;
    int* rowbeg = bcount + 256;
    int* rowend = rowbeg + NPAD;
    float* dinv = (float*)(rowend + NPAD);
    int* csr = (int*)(dinv + NPAD);
    unsigned short* g2 = (unsigned short*)(csr + NBKT * CSR_CAP);
    // aliases into d_out (51.2 MB): g1 at [0, 12.82MB), bbuf at [16MB, 28.9MB)
    unsigned short* g1 = (unsigned short*)out;            // dead before fused2 writes out
    unsigned int* bbuf = (unsigned int*)((char*)d_out + 16000000);  // dead after p2_build

    const int B = 256;
    const int EB = (E_EDGES + 4095) / 4096;  // 391

    // ---- build bucketed CSR + rowbeg/rowend/dinv ----
    p0_zero<<<1, B, 0, stream>>>(bcount, g1, g2);
    p1c_bin<<<EB, B, 0, stream>>>(src, dst, bcount, bbuf, E_EDGES);
    p2_build<<<NBKT, B, 0, stream>>>(bbuf, bcount, csr, rowbeg, rowend, dinv);

    // ---- layer 1 transform: g1 = bf16((x @ W1) * dinv) ----
    gemm1_kernel<<<(N_NODES + 63) / 64, B, 0, stream>>>(x, W1, dinv, g1);
    // ---- fused: aggregate(g1) + b1 + relu, @W2, *dinv -> g2 ----
    fused1_kernel<<<N_NODES / 16, B, 0, stream>>>(g1, csr, rowbeg, rowend, dinv, b1, W2, g2);
    // ---- fused: aggregate(g2) + b2, decoder @Wd + bd -> out ----
    fused2_kernel<<<N_NODES / 16, B, 0, stream>>>(g2, csr, rowbeg, rowend, dinv, b2, Wd, bd, out);
}